// Round 1
// baseline (785.513 us; speedup 1.0000x reference)
//
#include <hip/hip_runtime.h>

#define NTYPES 5

__device__ __forceinline__ unsigned fkey(float f) {
  unsigned u = __float_as_uint(f);
  return (u & 0x80000000u) ? ~u : (u | 0x80000000u);
}
__device__ __forceinline__ float fdec(unsigned k) {
  unsigned u = (k & 0x80000000u) ? (k ^ 0x80000000u) : ~k;
  return __uint_as_float(u);
}
__device__ __forceinline__ void fma4(float4& a, float s, const float4 w) {
  a.x = fmaf(s, w.x, a.x); a.y = fmaf(s, w.y, a.y);
  a.z = fmaf(s, w.z, a.z); a.w = fmaf(s, w.w, a.w);
}

// Generic 128-in -> 128-out row GEMM, j-split in halves of 64 outputs per block.
// W staged k-major in LDS (conflict-free b128 reads); input rows staged padded (+4).
// MODE 0: dst = src @ W^T, plus s_src/s_dst attention scalars (shuffle-reduced)
// MODE 1: dst = bias + src @ W^T              (h -> t)
// MODE 2: dst = relu(tbuf + src @ W^T)        (nh -> out)
template<int MODE>
__global__ __launch_bounds__(256) void k_gemm(
    const float* __restrict__ src, const float* __restrict__ Wg,
    int wstride4, int woff4,
    const float* __restrict__ Wattn,
    float* __restrict__ s_src, float* __restrict__ s_dst,
    const float* __restrict__ bias,
    const float* __restrict__ tbuf,
    float* __restrict__ dst, int n)
{
  __shared__ float wl[128 * 64];    // k-major: wl[k*64 + jl]
  __shared__ float nhl[32 * 132];   // 32 input rows, padded stride 132
  const int t = threadIdx.x;
  const int jhalf = blockIdx.x & 1;
  {
    const float4* Wg4 = (const float4*)Wg;
    #pragma unroll
    for (int i = 0; i < 8; ++i) {
      int id4 = i * 256 + t;
      int jl = id4 >> 5, k4 = id4 & 31;
      float4 w = Wg4[(size_t)(jhalf * 64 + jl) * wstride4 + woff4 + k4];
      wl[(k4 * 4 + 0) * 64 + jl] = w.x;
      wl[(k4 * 4 + 1) * 64 + jl] = w.y;
      wl[(k4 * 4 + 2) * 64 + jl] = w.z;
      wl[(k4 * 4 + 3) * 64 + jl] = w.w;
    }
  }
  const int jg = t & 15;   // 4-output group within the 64-out half
  const int np = t >> 4;   // node pair 0..15 -> nodes 2np, 2np+1
  float4 asrc, adst, bv;
  if (MODE == 0) {
    asrc = ((const float4*)Wattn)[jhalf * 16 + jg];
    adst = ((const float4*)Wattn)[32 + jhalf * 16 + jg];
  }
  if (MODE == 1) bv = ((const float4*)bias)[jhalf * 16 + jg];
  const int nchunk = (n + 31) >> 5;
  for (int chunk = blockIdx.x >> 1; chunk < nchunk; chunk += gridDim.x >> 1) {
    const int base = chunk << 5;
    __syncthreads();  // also covers W-stage before first compute
    for (int i = t; i < 1024; i += 256) {
      int node = i >> 5, k4i = i & 31;
      float4 v = make_float4(0.f, 0.f, 0.f, 0.f);
      if (base + node < n) v = ((const float4*)src)[(size_t)(base + node) * 32 + k4i];
      *(float4*)(nhl + node * 132 + k4i * 4) = v;
    }
    __syncthreads();
    const float* rowA = nhl + (2 * np) * 132;
    const float* rowB = rowA + 132;
    float4 aA, aB;
    if (MODE == 1) { aA = bv; aB = bv; }
    else { aA = make_float4(0,0,0,0); aB = make_float4(0,0,0,0); }
    #pragma unroll 8
    for (int k4 = 0; k4 < 32; ++k4) {
      float4 x = *(const float4*)(rowA + k4 * 4);
      float4 y = *(const float4*)(rowB + k4 * 4);
      const float* wb = wl + (k4 * 4) * 64 + jg * 4;
      float4 w0 = *(const float4*)(wb);
      float4 w1 = *(const float4*)(wb + 64);
      float4 w2 = *(const float4*)(wb + 128);
      float4 w3 = *(const float4*)(wb + 192);
      fma4(aA, x.x, w0); fma4(aA, x.y, w1); fma4(aA, x.z, w2); fma4(aA, x.w, w3);
      fma4(aB, y.x, w0); fma4(aB, y.y, w1); fma4(aB, y.z, w2); fma4(aB, y.w, w3);
    }
    const int nA = base + 2 * np, nB = nA + 1;
    const size_t oA = (size_t)nA * 32 + jhalf * 16 + jg;
    const size_t oB = (size_t)nB * 32 + jhalf * 16 + jg;
    if (MODE == 0) {
      float sA = aA.x*asrc.x + aA.y*asrc.y + aA.z*asrc.z + aA.w*asrc.w;
      float dA = aA.x*adst.x + aA.y*adst.y + aA.z*adst.z + aA.w*adst.w;
      float sB = aB.x*asrc.x + aB.y*asrc.y + aB.z*asrc.z + aB.w*asrc.w;
      float dB = aB.x*adst.x + aB.y*adst.y + aB.z*adst.z + aB.w*adst.w;
      #pragma unroll
      for (int m = 8; m >= 1; m >>= 1) {
        sA += __shfl_xor(sA, m); dA += __shfl_xor(dA, m);
        sB += __shfl_xor(sB, m); dB += __shfl_xor(dB, m);
      }
      if (nA < n) {
        ((float4*)dst)[oA] = aA;
        if (jg == 0) { atomicAdd(&s_src[nA], sA); atomicAdd(&s_dst[nA], dA); }
      }
      if (nB < n) {
        ((float4*)dst)[oB] = aB;
        if (jg == 0) { atomicAdd(&s_src[nB], sB); atomicAdd(&s_dst[nB], dB); }
      }
    } else if (MODE == 1) {
      if (nA < n) ((float4*)dst)[oA] = aA;
      if (nB < n) ((float4*)dst)[oB] = aB;
    } else {
      if (nA < n) {
        float4 tv = ((const float4*)tbuf)[oA];
        ((float4*)dst)[oA] = make_float4(fmaxf(tv.x + aA.x, 0.f), fmaxf(tv.y + aA.y, 0.f),
                                         fmaxf(tv.z + aA.z, 0.f), fmaxf(tv.w + aA.w, 0.f));
      }
      if (nB < n) {
        float4 tv = ((const float4*)tbuf)[oB];
        ((float4*)dst)[oB] = make_float4(fmaxf(tv.x + aB.x, 0.f), fmaxf(tv.y + aB.y, 0.f),
                                         fmaxf(tv.z + aB.z, 0.f), fmaxf(tv.w + aB.w, 0.f));
      }
    }
  }
}

// ef = leakyrelu(s_src[src] + s_dst[dst]); seg-max via encoded atomicMax
__global__ __launch_bounds__(256) void k_edge_max(
    const int* __restrict__ ei, const int* __restrict__ ey,
    const float* __restrict__ s_src, const float* __restrict__ s_dst,
    float* __restrict__ ef, unsigned* __restrict__ mkey, int e)
{
  int i = blockIdx.x * 256 + threadIdx.x;
  if (i >= e) return;
  int s = ei[i], d = ei[e + i];
  float v = s_src[s] + s_dst[d];
  v = v >= 0.f ? v : 0.2f * v;
  ef[i] = v;
  atomicMax(&mkey[d * NTYPES + ey[i]], fkey(v));
}

// ex = exp(ef - m[seg]) stored over ef; denom[seg] += ex
__global__ __launch_bounds__(256) void k_edge_den(
    const int* __restrict__ ei, const int* __restrict__ ey,
    float* __restrict__ ef, const unsigned* __restrict__ mkey,
    float* __restrict__ denom, int e)
{
  int i = blockIdx.x * 256 + threadIdx.x;
  if (i >= e) return;
  int d = ei[e + i];
  int seg = d * NTYPES + ey[i];
  float ex = __expf(ef[i] - fdec(mkey[seg]));
  ef[i] = ex;
  atomicAdd(&denom[seg], ex);
}

// h[dst] += (ex/denom[seg]) * nfl[src]   — 2 edges per 256-thread block
__global__ __launch_bounds__(256) void k_scatter(
    const int* __restrict__ ei, const int* __restrict__ ey,
    const float* __restrict__ ex, const float* __restrict__ denom,
    const float* __restrict__ nfl, float* __restrict__ h, int e)
{
  int eidx = blockIdx.x * 2 + (threadIdx.x >> 7);
  if (eidx >= e) return;
  int dcomp = threadIdx.x & 127;
  int s = ei[eidx], d = ei[e + eidx];
  int seg = d * NTYPES + ey[eidx];
  float alpha = ex[eidx] / denom[seg];
  atomicAdd(&h[(size_t)d * 128 + dcomp], alpha * nfl[(size_t)s * 128 + dcomp]);
}

extern "C" void kernel_launch(void* const* d_in, const int* in_sizes, int n_in,
                              void* d_out, int out_size, void* d_ws, size_t ws_size,
                              hipStream_t stream) {
  const float* nh     = (const float*)d_in[0];
  const int*   edge_y = (const int*)d_in[1];
  const int*   ei     = (const int*)d_in[2];
  const float* W_nf   = (const float*)d_in[3];
  const float* W_attn = (const float*)d_in[4];
  const float* W_out  = (const float*)d_in[5];
  const float* b_out  = (const float*)d_in[6];
  float* out = (float*)d_out;
  const int n = in_sizes[0] / 128;
  const int e = in_sizes[1];

  // workspace layout (floats)
  float* nfl   = (float*)d_ws;                 // n*128  (reused as t-buffer later)
  float* s_src = nfl + (size_t)n * 128;        // n
  float* s_dst = s_src + n;                    // n
  float* ef    = s_dst + n;                    // e
  unsigned* mkey = (unsigned*)(ef + e);        // n*NTYPES
  float* denom = (float*)(mkey + (size_t)n * NTYPES); // n*NTYPES

  hipMemsetAsync(s_src, 0, (size_t)2 * n * sizeof(float), stream);
  hipMemsetAsync(mkey, 0, (size_t)2 * n * NTYPES * sizeof(float), stream);
  hipMemsetAsync(d_out, 0, (size_t)out_size * sizeof(float), stream);

  // 1) nfl = nh @ W_nf^T  (+ s_src, s_dst)
  k_gemm<0><<<2048, 256, 0, stream>>>(nh, W_nf, 32, 0, W_attn, s_src, s_dst,
                                      nullptr, nullptr, nfl, n);
  // 2) edge logits + segment max
  k_edge_max<<<(e + 255) / 256, 256, 0, stream>>>(ei, edge_y, s_src, s_dst, ef, mkey, e);
  // 3) exp + segment sum
  k_edge_den<<<(e + 255) / 256, 256, 0, stream>>>(ei, edge_y, ef, mkey, denom, e);
  // 4) h (in d_out) += alpha * nfl[src]
  k_scatter<<<(e + 1) / 2, 256, 0, stream>>>(ei, edge_y, ef, denom, nfl, out, e);
  // 5) t = b + h @ Wo2^T   (t reuses nfl region; W_out cols 128..255)
  k_gemm<1><<<2048, 256, 0, stream>>>(out, W_out, 64, 32, nullptr, nullptr, nullptr,
                                      b_out, nullptr, nfl, n);
  // 6) out = relu(t + nh @ Wo1^T)
  k_gemm<2><<<2048, 256, 0, stream>>>(nh, W_out, 64, 0, nullptr, nullptr, nullptr,
                                      nullptr, nfl, out, n);
}

// Round 2
// 521.490 us; speedup vs baseline: 1.5063x; 1.5063x over previous
//
#include <hip/hip_runtime.h>

#define NTYPES 5

__device__ __forceinline__ unsigned fkey(float f) {
  unsigned u = __float_as_uint(f);
  return (u & 0x80000000u) ? ~u : (u | 0x80000000u);
}
__device__ __forceinline__ float fdec(unsigned k) {
  unsigned u = (k & 0x80000000u) ? (k ^ 0x80000000u) : ~k;
  return __uint_as_float(u);
}
__device__ __forceinline__ void fma4(float4& a, float s, const float4 w) {
  a.x = fmaf(s, w.x, a.x); a.y = fmaf(s, w.y, a.y);
  a.z = fmaf(s, w.z, a.z); a.w = fmaf(s, w.w, a.w);
}

// Generic 128-in -> 128-out row GEMM, j-split in halves of 64 outputs per block.
// MODE 0: dst = src @ W^T, plus s_src/s_dst attention scalars (shuffle-reduced)
// MODE 1: dst = bias + src @ W^T              (h -> t)
// MODE 2: dst = relu(tbuf + src @ W^T)        (nh -> out)
template<int MODE>
__global__ __launch_bounds__(256) void k_gemm(
    const float* __restrict__ src, const float* __restrict__ Wg,
    int wstride4, int woff4,
    const float* __restrict__ Wattn,
    float* __restrict__ s_src, float* __restrict__ s_dst,
    const float* __restrict__ bias,
    const float* __restrict__ tbuf,
    float* __restrict__ dst, int n)
{
  __shared__ float wl[128 * 64];    // k-major: wl[k*64 + jl]
  __shared__ float nhl[32 * 132];   // 32 input rows, padded stride 132
  const int t = threadIdx.x;
  const int jhalf = blockIdx.x & 1;
  {
    const float4* Wg4 = (const float4*)Wg;
    #pragma unroll
    for (int i = 0; i < 8; ++i) {
      int id4 = i * 256 + t;
      int jl = id4 >> 5, k4 = id4 & 31;
      float4 w = Wg4[(size_t)(jhalf * 64 + jl) * wstride4 + woff4 + k4];
      wl[(k4 * 4 + 0) * 64 + jl] = w.x;
      wl[(k4 * 4 + 1) * 64 + jl] = w.y;
      wl[(k4 * 4 + 2) * 64 + jl] = w.z;
      wl[(k4 * 4 + 3) * 64 + jl] = w.w;
    }
  }
  const int jg = t & 15;
  const int np = t >> 4;
  float4 asrc, adst, bv;
  if (MODE == 0) {
    asrc = ((const float4*)Wattn)[jhalf * 16 + jg];
    adst = ((const float4*)Wattn)[32 + jhalf * 16 + jg];
  }
  if (MODE == 1) bv = ((const float4*)bias)[jhalf * 16 + jg];
  const int nchunk = (n + 31) >> 5;
  for (int chunk = blockIdx.x >> 1; chunk < nchunk; chunk += gridDim.x >> 1) {
    const int base = chunk << 5;
    __syncthreads();
    for (int i = t; i < 1024; i += 256) {
      int node = i >> 5, k4i = i & 31;
      float4 v = make_float4(0.f, 0.f, 0.f, 0.f);
      if (base + node < n) v = ((const float4*)src)[(size_t)(base + node) * 32 + k4i];
      *(float4*)(nhl + node * 132 + k4i * 4) = v;
    }
    __syncthreads();
    const float* rowA = nhl + (2 * np) * 132;
    const float* rowB = rowA + 132;
    float4 aA, aB;
    if (MODE == 1) { aA = bv; aB = bv; }
    else { aA = make_float4(0,0,0,0); aB = make_float4(0,0,0,0); }
    #pragma unroll 8
    for (int k4 = 0; k4 < 32; ++k4) {
      float4 x = *(const float4*)(rowA + k4 * 4);
      float4 y = *(const float4*)(rowB + k4 * 4);
      const float* wb = wl + (k4 * 4) * 64 + jg * 4;
      float4 w0 = *(const float4*)(wb);
      float4 w1 = *(const float4*)(wb + 64);
      float4 w2 = *(const float4*)(wb + 128);
      float4 w3 = *(const float4*)(wb + 192);
      fma4(aA, x.x, w0); fma4(aA, x.y, w1); fma4(aA, x.z, w2); fma4(aA, x.w, w3);
      fma4(aB, y.x, w0); fma4(aB, y.y, w1); fma4(aB, y.z, w2); fma4(aB, y.w, w3);
    }
    const int nA = base + 2 * np, nB = nA + 1;
    const size_t oA = (size_t)nA * 32 + jhalf * 16 + jg;
    const size_t oB = (size_t)nB * 32 + jhalf * 16 + jg;
    if (MODE == 0) {
      float sA = aA.x*asrc.x + aA.y*asrc.y + aA.z*asrc.z + aA.w*asrc.w;
      float dA = aA.x*adst.x + aA.y*adst.y + aA.z*adst.z + aA.w*adst.w;
      float sB = aB.x*asrc.x + aB.y*asrc.y + aB.z*asrc.z + aB.w*asrc.w;
      float dB = aB.x*adst.x + aB.y*adst.y + aB.z*adst.z + aB.w*adst.w;
      #pragma unroll
      for (int m = 8; m >= 1; m >>= 1) {
        sA += __shfl_xor(sA, m); dA += __shfl_xor(dA, m);
        sB += __shfl_xor(sB, m); dB += __shfl_xor(dB, m);
      }
      if (nA < n) {
        ((float4*)dst)[oA] = aA;
        if (jg == 0) { atomicAdd(&s_src[nA], sA); atomicAdd(&s_dst[nA], dA); }
      }
      if (nB < n) {
        ((float4*)dst)[oB] = aB;
        if (jg == 0) { atomicAdd(&s_src[nB], sB); atomicAdd(&s_dst[nB], dB); }
      }
    } else if (MODE == 1) {
      if (nA < n) ((float4*)dst)[oA] = aA;
      if (nB < n) ((float4*)dst)[oB] = aB;
    } else {
      if (nA < n) {
        float4 tv = ((const float4*)tbuf)[oA];
        ((float4*)dst)[oA] = make_float4(fmaxf(tv.x + aA.x, 0.f), fmaxf(tv.y + aA.y, 0.f),
                                         fmaxf(tv.z + aA.z, 0.f), fmaxf(tv.w + aA.w, 0.f));
      }
      if (nB < n) {
        float4 tv = ((const float4*)tbuf)[oB];
        ((float4*)dst)[oB] = make_float4(fmaxf(tv.x + aB.x, 0.f), fmaxf(tv.y + aB.y, 0.f),
                                         fmaxf(tv.z + aB.z, 0.f), fmaxf(tv.w + aB.w, 0.f));
      }
    }
  }
}

// ef = leakyrelu(s_src[src] + s_dst[dst]); seg-max via encoded atomicMax; deg histogram
__global__ __launch_bounds__(256) void k_edge_max(
    const int* __restrict__ ei, const int* __restrict__ ey,
    const float* __restrict__ s_src, const float* __restrict__ s_dst,
    float* __restrict__ ef, unsigned* __restrict__ mkey, int* __restrict__ deg, int e)
{
  int i = blockIdx.x * 256 + threadIdx.x;
  if (i >= e) return;
  int s = ei[i], d = ei[e + i];
  float v = s_src[s] + s_dst[d];
  v = v >= 0.f ? v : 0.2f * v;
  ef[i] = v;
  atomicMax(&mkey[d * NTYPES + ey[i]], fkey(v));
  atomicAdd(&deg[d], 1);
}

// ex = exp(ef - m[seg]) stored over ef; denom[seg] += ex
__global__ __launch_bounds__(256) void k_edge_den(
    const int* __restrict__ ei, const int* __restrict__ ey,
    float* __restrict__ ef, const unsigned* __restrict__ mkey,
    float* __restrict__ denom, int e)
{
  int i = blockIdx.x * 256 + threadIdx.x;
  if (i >= e) return;
  int d = ei[e + i];
  int seg = d * NTYPES + ey[i];
  float ex = __expf(ef[i] - fdec(mkey[seg]));
  ef[i] = ex;
  atomicAdd(&denom[seg], ex);
}

// ---- exclusive scan over deg (n up to 256*1024) ----
__global__ __launch_bounds__(256) void k_scan1(
    const int* __restrict__ deg, int* __restrict__ base, int* __restrict__ bsum, int n)
{
  __shared__ int ws[4];
  int t = threadIdx.x;
  int g0 = blockIdx.x * 1024 + t * 4;
  int4 v = make_int4(0, 0, 0, 0);
  if (g0 + 3 < n) v = *(const int4*)(deg + g0);
  else {
    if (g0     < n) v.x = deg[g0];
    if (g0 + 1 < n) v.y = deg[g0 + 1];
    if (g0 + 2 < n) v.z = deg[g0 + 2];
    if (g0 + 3 < n) v.w = deg[g0 + 3];
  }
  int s = v.x + v.y + v.z + v.w;
  int inc = s;
  #pragma unroll
  for (int d = 1; d < 64; d <<= 1) {
    int o = __shfl_up(inc, d);
    if ((t & 63) >= d) inc += o;
  }
  int wid = t >> 6;
  if ((t & 63) == 63) ws[wid] = inc;
  __syncthreads();
  int woff = 0;
  for (int w = 0; w < wid; ++w) woff += ws[w];
  int exc = woff + inc - s;
  if (g0 + 3 < n) {
    *(int4*)(base + g0) = make_int4(exc, exc + v.x, exc + v.x + v.y, exc + v.x + v.y + v.z);
  } else {
    if (g0     < n) base[g0]     = exc;
    if (g0 + 1 < n) base[g0 + 1] = exc + v.x;
    if (g0 + 2 < n) base[g0 + 2] = exc + v.x + v.y;
  }
  if (t == 255) bsum[blockIdx.x] = woff + inc;
}

__global__ __launch_bounds__(256) void k_scan2(
    const int* __restrict__ bsum, int* __restrict__ boff, int nb)
{
  __shared__ int ws[4];
  int t = threadIdx.x;
  int x = t < nb ? bsum[t] : 0;
  int inc = x;
  #pragma unroll
  for (int d = 1; d < 64; d <<= 1) {
    int o = __shfl_up(inc, d);
    if ((t & 63) >= d) inc += o;
  }
  int wid = t >> 6;
  if ((t & 63) == 63) ws[wid] = inc;
  __syncthreads();
  int woff = 0;
  for (int w = 0; w < wid; ++w) woff += ws[w];
  if (t < nb) boff[t] = woff + inc - x;
}

__global__ __launch_bounds__(256) void k_scan3(
    int* __restrict__ base, const int* __restrict__ boff,
    int* __restrict__ cur, int n)
{
  int i = blockIdx.x * 256 + threadIdx.x;
  if (i < n) {
    int b = base[i] + boff[i >> 10];
    base[i] = b;
    cur[i] = b;
  }
}

// pack (src, alpha) records into per-dst contiguous ranges
__global__ __launch_bounds__(256) void k_fill(
    const int* __restrict__ ei, const int* __restrict__ ey,
    const float* __restrict__ ex, const float* __restrict__ denom,
    int* __restrict__ cur, float2* __restrict__ rec, int e)
{
  int i = blockIdx.x * 256 + threadIdx.x;
  if (i >= e) return;
  int s = ei[i], d = ei[e + i];
  float a = ex[i] / denom[d * NTYPES + ey[i]];
  int pos = atomicAdd(&cur[d], 1);
  rec[pos] = make_float2(__int_as_float(s), a);
}

// h[d] = sum_j alpha_j * nfl[src_j]  — one wave per dst, lane owns 2 comps
__global__ __launch_bounds__(256) void k_aggregate(
    const float2* __restrict__ rec, const int* __restrict__ base,
    const int* __restrict__ deg, const float* __restrict__ nfl,
    float* __restrict__ h, int n)
{
  int d = blockIdx.x * 4 + (threadIdx.x >> 6);
  if (d >= n) return;
  int lane = threadIdx.x & 63;
  int b = base[d], dg = deg[d];
  float accx = 0.f, accy = 0.f;
  for (int j0 = 0; j0 < dg; j0 += 64) {
    int m = min(64, dg - j0);
    float2 r = make_float2(0.f, 0.f);
    if (lane < m) r = rec[b + j0 + lane];
    int srcv = __float_as_int(r.x);
    float av = r.y;
    int j = 0;
    for (; j + 4 <= m; j += 4) {
      int s0 = __shfl(srcv, j),     s1 = __shfl(srcv, j + 1);
      int s2 = __shfl(srcv, j + 2), s3 = __shfl(srcv, j + 3);
      float a0 = __shfl(av, j),     a1 = __shfl(av, j + 1);
      float a2 = __shfl(av, j + 2), a3 = __shfl(av, j + 3);
      float2 x0 = *(const float2*)(nfl + (size_t)s0 * 128 + 2 * lane);
      float2 x1 = *(const float2*)(nfl + (size_t)s1 * 128 + 2 * lane);
      float2 x2 = *(const float2*)(nfl + (size_t)s2 * 128 + 2 * lane);
      float2 x3 = *(const float2*)(nfl + (size_t)s3 * 128 + 2 * lane);
      accx = fmaf(a0, x0.x, accx); accy = fmaf(a0, x0.y, accy);
      accx = fmaf(a1, x1.x, accx); accy = fmaf(a1, x1.y, accy);
      accx = fmaf(a2, x2.x, accx); accy = fmaf(a2, x2.y, accy);
      accx = fmaf(a3, x3.x, accx); accy = fmaf(a3, x3.y, accy);
    }
    for (; j < m; ++j) {
      int s0 = __shfl(srcv, j);
      float a0 = __shfl(av, j);
      float2 x0 = *(const float2*)(nfl + (size_t)s0 * 128 + 2 * lane);
      accx = fmaf(a0, x0.x, accx); accy = fmaf(a0, x0.y, accy);
    }
  }
  *(float2*)(h + (size_t)d * 128 + 2 * lane) = make_float2(accx, accy);
}

extern "C" void kernel_launch(void* const* d_in, const int* in_sizes, int n_in,
                              void* d_out, int out_size, void* d_ws, size_t ws_size,
                              hipStream_t stream) {
  const float* nh     = (const float*)d_in[0];
  const int*   edge_y = (const int*)d_in[1];
  const int*   ei     = (const int*)d_in[2];
  const float* W_nf   = (const float*)d_in[3];
  const float* W_attn = (const float*)d_in[4];
  const float* W_out  = (const float*)d_in[5];
  const float* b_out  = (const float*)d_in[6];
  float* out = (float*)d_out;
  const int n = in_sizes[0] / 128;
  const int e = in_sizes[1];
  const int nb = (n + 1023) / 1024;

  // workspace layout (floats)
  float* nfl   = (float*)d_ws;                         // n*128 (reused as t later)
  float* s_src = nfl + (size_t)n * 128;                // n
  float* s_dst = s_src + n;                            // n
  float* ef    = s_dst + n;                            // e
  unsigned* mkey = (unsigned*)(ef + e);                // n*NTYPES
  float* denom = (float*)(mkey + (size_t)n * NTYPES);  // n*NTYPES
  int*   deg   = (int*)(denom + (size_t)n * NTYPES);   // n
  int*   base  = deg + n;                              // n
  int*   cur   = base + n;                             // n
  int*   bsum  = cur + n;                              // 256
  int*   boff  = bsum + 256;                           // 256
  float2* rec  = (float2*)(boff + 256);                // e float2

  hipMemsetAsync(s_src, 0, (size_t)2 * n * sizeof(float), stream);
  hipMemsetAsync(mkey, 0, (size_t)2 * n * NTYPES * sizeof(float), stream);
  hipMemsetAsync(deg, 0, (size_t)n * sizeof(int), stream);

  // 1) nfl = nh @ W_nf^T  (+ s_src, s_dst)
  k_gemm<0><<<2048, 256, 0, stream>>>(nh, W_nf, 32, 0, W_attn, s_src, s_dst,
                                      nullptr, nullptr, nfl, n);
  // 2) edge logits + segment max + deg histogram
  k_edge_max<<<(e + 255) / 256, 256, 0, stream>>>(ei, edge_y, s_src, s_dst, ef, mkey, deg, e);
  // 3) exp + segment sum
  k_edge_den<<<(e + 255) / 256, 256, 0, stream>>>(ei, edge_y, ef, mkey, denom, e);
  // 4) exclusive scan deg -> base, cur
  k_scan1<<<nb, 256, 0, stream>>>(deg, base, bsum, n);
  k_scan2<<<1, 256, 0, stream>>>(bsum, boff, nb);
  k_scan3<<<(n + 255) / 256, 256, 0, stream>>>(base, boff, cur, n);
  // 5) pack (src, alpha) per dst
  k_fill<<<(e + 255) / 256, 256, 0, stream>>>(ei, edge_y, ef, denom, cur, rec, e);
  // 6) h (in d_out) = gather-aggregate
  k_aggregate<<<(n + 3) / 4, 256, 0, stream>>>(rec, base, deg, nfl, out, n);
  // 7) t = b + h @ Wo2^T   (t reuses nfl region; W_out cols 128..255)
  k_gemm<1><<<2048, 256, 0, stream>>>(out, W_out, 64, 32, nullptr, nullptr, nullptr,
                                      b_out, nullptr, nfl, n);
  // 8) out = relu(t + nh @ Wo1^T)
  k_gemm<2><<<2048, 256, 0, stream>>>(nh, W_out, 64, 0, nullptr, nullptr, nullptr,
                                      nullptr, nfl, out, n);
}

// Round 3
// 362.152 us; speedup vs baseline: 2.1690x; 1.4400x over previous
//
#include <hip/hip_runtime.h>

#define NTYPES 5

typedef _Float16 half8 __attribute__((ext_vector_type(8)));
typedef _Float16 half4v __attribute__((ext_vector_type(4)));
typedef float float4v __attribute__((ext_vector_type(4)));

__device__ __forceinline__ unsigned fkey(float f) {
  unsigned u = __float_as_uint(f);
  return (u & 0x80000000u) ? ~u : (u | 0x80000000u);
}
__device__ __forceinline__ float fdec(unsigned k) {
  unsigned u = (k & 0x80000000u) ? (k ^ 0x80000000u) : ~k;
  return __uint_as_float(u);
}

// Stage `rows` x 128 f32 tile (row stride stride4 float4s, col offset off4) into
// LDS as f16, row stride 256 B, with XOR swizzle byte ^= (row&7)<<4.
__device__ __forceinline__ void stage_tile_f16(
    _Float16* lds, const float* __restrict__ g, int rows, int stride4, int off4,
    int grow0, int nmax, int t)
{
  const float4* g4 = (const float4*)g;
  for (int i = t; i < rows * 32; i += 256) {
    int row = i >> 5, q = i & 31;
    float4 v = make_float4(0.f, 0.f, 0.f, 0.f);
    int gr = grow0 + row;
    if (gr < nmax) v = g4[(size_t)gr * stride4 + off4 + q];
    half4v hv = { (_Float16)v.x, (_Float16)v.y, (_Float16)v.z, (_Float16)v.w };
    int byte = row * 256 + ((q * 8) ^ ((row & 7) << 4));
    *(half4v*)((char*)lds + byte) = hv;
  }
}

// Read an 8-halfword MFMA fragment (row-major tile, swizzled as above).
__device__ __forceinline__ half8 frag_ld(const _Float16* lds, int row, int khw) {
  int byte = row * 256 + ((khw * 2) ^ ((row & 7) << 4));
  return *(const half8*)((const char*)lds + byte);
}

// MFMA GEMM: dst[n x 128] = f(src[n x 128] @ W^T). W rows are 128-float slices
// of Wg (row stride wstride4 float4s, col offset woff4).
// MODE 0: dst = src @ W^T, plus s_src/s_dst = dst @ a_src/a_dst (plain stores)
// MODE 1: dst = bias + src @ W^T
// MODE 2: dst = relu(tbuf + src @ W^T)
template<int MODE>
__global__ __launch_bounds__(256) void k_gemm(
    const float* __restrict__ src, const float* __restrict__ Wg,
    int wstride4, int woff4,
    const float* __restrict__ Wattn,
    float* __restrict__ s_src, float* __restrict__ s_dst,
    const float* __restrict__ bias,
    const float* __restrict__ tbuf,
    float* __restrict__ dst, int n)
{
  __shared__ _Float16 wh[128 * 128];  // W tile, [j][k], 32 KB
  __shared__ _Float16 xh[64 * 128];   // node tile, [node][k], 16 KB
  const int t = threadIdx.x;
  const int lane = t & 63;
  const int wv = t >> 6;        // wave 0..3 -> node rows wv*16..wv*16+15
  const int r16 = lane & 15;
  const int g = lane >> 4;

  stage_tile_f16(wh, Wg, 128, wstride4, woff4, 0, 1 << 30, t);

  float asrc[8], adst[8], bv[8];
  if (MODE == 0) {
    #pragma unroll
    for (int nf = 0; nf < 8; ++nf) {
      asrc[nf] = Wattn[nf * 16 + r16];
      adst[nf] = Wattn[128 + nf * 16 + r16];
    }
  }
  if (MODE == 1) {
    #pragma unroll
    for (int nf = 0; nf < 8; ++nf) bv[nf] = bias[nf * 16 + r16];
  }

  const int nchunk = (n + 63) >> 6;
  for (int c = blockIdx.x; c < nchunk; c += gridDim.x) {
    const int base = c << 6;
    __syncthreads();   // xh reuse from prev iter; also covers wh stage (iter 0)
    stage_tile_f16(xh, src, 64, 32, 0, base, n, t);
    __syncthreads();

    float4v acc[8];
    #pragma unroll
    for (int nf = 0; nf < 8; ++nf) acc[nf] = (float4v){0.f, 0.f, 0.f, 0.f};
    #pragma unroll
    for (int s = 0; s < 4; ++s) {
      half8 a = frag_ld(xh, wv * 16 + r16, s * 32 + g * 8);
      #pragma unroll
      for (int nf = 0; nf < 8; ++nf) {
        half8 b = frag_ld(wh, nf * 16 + r16, s * 32 + g * 8);
        acc[nf] = __builtin_amdgcn_mfma_f32_16x16x32_f16(a, b, acc[nf], 0, 0, 0);
      }
    }

    // D store: lane holds D[wv*16 + g*4 + rr][nf*16 + r16]
    #pragma unroll
    for (int rr = 0; rr < 4; ++rr) {
      int node = base + wv * 16 + g * 4 + rr;
      if (node >= n) continue;
      size_t ro = (size_t)node * 128;
      #pragma unroll
      for (int nf = 0; nf < 8; ++nf) {
        int col = nf * 16 + r16;
        float v = acc[nf][rr];
        if (MODE == 1) v += bv[nf];
        if (MODE == 2) v = fmaxf(v + tbuf[ro + col], 0.f);
        dst[ro + col] = v;
      }
    }
    if (MODE == 0) {
      float ss[4] = {0.f, 0.f, 0.f, 0.f}, sd[4] = {0.f, 0.f, 0.f, 0.f};
      #pragma unroll
      for (int nf = 0; nf < 8; ++nf) {
        #pragma unroll
        for (int rr = 0; rr < 4; ++rr) {
          ss[rr] = fmaf(acc[nf][rr], asrc[nf], ss[rr]);
          sd[rr] = fmaf(acc[nf][rr], adst[nf], sd[rr]);
        }
      }
      #pragma unroll
      for (int m = 1; m <= 8; m <<= 1) {
        #pragma unroll
        for (int rr = 0; rr < 4; ++rr) {
          ss[rr] += __shfl_xor(ss[rr], m);
          sd[rr] += __shfl_xor(sd[rr], m);
        }
      }
      if (r16 == 0) {
        #pragma unroll
        for (int rr = 0; rr < 4; ++rr) {
          int node = base + wv * 16 + g * 4 + rr;
          if (node < n) { s_src[node] = ss[rr]; s_dst[node] = sd[rr]; }
        }
      }
    }
  }
}

// ef = leakyrelu(s_src[src] + s_dst[dst]); seg-max via encoded atomicMax; deg histogram
__global__ __launch_bounds__(256) void k_edge_max(
    const int* __restrict__ ei, const int* __restrict__ ey,
    const float* __restrict__ s_src, const float* __restrict__ s_dst,
    float* __restrict__ ef, unsigned* __restrict__ mkey, int* __restrict__ deg, int e)
{
  int i = blockIdx.x * 256 + threadIdx.x;
  if (i >= e) return;
  int s = ei[i], d = ei[e + i];
  float v = s_src[s] + s_dst[d];
  v = v >= 0.f ? v : 0.2f * v;
  ef[i] = v;
  atomicMax(&mkey[d * NTYPES + ey[i]], fkey(v));
  atomicAdd(&deg[d], 1);
}

// ex = exp(ef - m[seg]) stored over ef; denom[seg] += ex
__global__ __launch_bounds__(256) void k_edge_den(
    const int* __restrict__ ei, const int* __restrict__ ey,
    float* __restrict__ ef, const unsigned* __restrict__ mkey,
    float* __restrict__ denom, int e)
{
  int i = blockIdx.x * 256 + threadIdx.x;
  if (i >= e) return;
  int d = ei[e + i];
  int seg = d * NTYPES + ey[i];
  float ex = __expf(ef[i] - fdec(mkey[seg]));
  ef[i] = ex;
  atomicAdd(&denom[seg], ex);
}

// ---- exclusive scan over deg ----
__global__ __launch_bounds__(256) void k_scan1(
    const int* __restrict__ deg, int* __restrict__ base, int* __restrict__ bsum, int n)
{
  __shared__ int ws[4];
  int t = threadIdx.x;
  int g0 = blockIdx.x * 1024 + t * 4;
  int4 v = make_int4(0, 0, 0, 0);
  if (g0 + 3 < n) v = *(const int4*)(deg + g0);
  else {
    if (g0     < n) v.x = deg[g0];
    if (g0 + 1 < n) v.y = deg[g0 + 1];
    if (g0 + 2 < n) v.z = deg[g0 + 2];
    if (g0 + 3 < n) v.w = deg[g0 + 3];
  }
  int s = v.x + v.y + v.z + v.w;
  int inc = s;
  #pragma unroll
  for (int d = 1; d < 64; d <<= 1) {
    int o = __shfl_up(inc, d);
    if ((t & 63) >= d) inc += o;
  }
  int wid = t >> 6;
  if ((t & 63) == 63) ws[wid] = inc;
  __syncthreads();
  int woff = 0;
  for (int w = 0; w < wid; ++w) woff += ws[w];
  int exc = woff + inc - s;
  if (g0 + 3 < n) {
    *(int4*)(base + g0) = make_int4(exc, exc + v.x, exc + v.x + v.y, exc + v.x + v.y + v.z);
  } else {
    if (g0     < n) base[g0]     = exc;
    if (g0 + 1 < n) base[g0 + 1] = exc + v.x;
    if (g0 + 2 < n) base[g0 + 2] = exc + v.x + v.y;
  }
  if (t == 255) bsum[blockIdx.x] = woff + inc;
}

__global__ __launch_bounds__(256) void k_scan2(
    const int* __restrict__ bsum, int* __restrict__ boff, int nb)
{
  __shared__ int ws[4];
  int t = threadIdx.x;
  int x = t < nb ? bsum[t] : 0;
  int inc = x;
  #pragma unroll
  for (int d = 1; d < 64; d <<= 1) {
    int o = __shfl_up(inc, d);
    if ((t & 63) >= d) inc += o;
  }
  int wid = t >> 6;
  if ((t & 63) == 63) ws[wid] = inc;
  __syncthreads();
  int woff = 0;
  for (int w = 0; w < wid; ++w) woff += ws[w];
  if (t < nb) boff[t] = woff + inc - x;
}

__global__ __launch_bounds__(256) void k_scan3(
    int* __restrict__ base, const int* __restrict__ boff,
    int* __restrict__ cur, int n)
{
  int i = blockIdx.x * 256 + threadIdx.x;
  if (i < n) {
    int b = base[i] + boff[i >> 10];
    base[i] = b;
    cur[i] = b;
  }
}

// pack (src, alpha) records into per-dst contiguous ranges
__global__ __launch_bounds__(256) void k_fill(
    const int* __restrict__ ei, const int* __restrict__ ey,
    const float* __restrict__ ex, const float* __restrict__ denom,
    int* __restrict__ cur, float2* __restrict__ rec, int e)
{
  int i = blockIdx.x * 256 + threadIdx.x;
  if (i >= e) return;
  int s = ei[i], d = ei[e + i];
  float a = ex[i] / denom[d * NTYPES + ey[i]];
  int pos = atomicAdd(&cur[d], 1);
  rec[pos] = make_float2(__int_as_float(s), a);
}

// h[d] = sum_j alpha_j * nfl[src_j]  — one wave per dst, lane owns 2 comps
__global__ __launch_bounds__(256) void k_aggregate(
    const float2* __restrict__ rec, const int* __restrict__ base,
    const int* __restrict__ deg, const float* __restrict__ nfl,
    float* __restrict__ h, int n)
{
  int d = blockIdx.x * 4 + (threadIdx.x >> 6);
  if (d >= n) return;
  int lane = threadIdx.x & 63;
  int b = base[d], dg = deg[d];
  float accx = 0.f, accy = 0.f;
  for (int j0 = 0; j0 < dg; j0 += 64) {
    int m = min(64, dg - j0);
    float2 r = make_float2(0.f, 0.f);
    if (lane < m) r = rec[b + j0 + lane];
    int srcv = __float_as_int(r.x);
    float av = r.y;
    int j = 0;
    for (; j + 4 <= m; j += 4) {
      int s0 = __shfl(srcv, j),     s1 = __shfl(srcv, j + 1);
      int s2 = __shfl(srcv, j + 2), s3 = __shfl(srcv, j + 3);
      float a0 = __shfl(av, j),     a1 = __shfl(av, j + 1);
      float a2 = __shfl(av, j + 2), a3 = __shfl(av, j + 3);
      float2 x0 = *(const float2*)(nfl + (size_t)s0 * 128 + 2 * lane);
      float2 x1 = *(const float2*)(nfl + (size_t)s1 * 128 + 2 * lane);
      float2 x2 = *(const float2*)(nfl + (size_t)s2 * 128 + 2 * lane);
      float2 x3 = *(const float2*)(nfl + (size_t)s3 * 128 + 2 * lane);
      accx = fmaf(a0, x0.x, accx); accy = fmaf(a0, x0.y, accy);
      accx = fmaf(a1, x1.x, accx); accy = fmaf(a1, x1.y, accy);
      accx = fmaf(a2, x2.x, accx); accy = fmaf(a2, x2.y, accy);
      accx = fmaf(a3, x3.x, accx); accy = fmaf(a3, x3.y, accy);
    }
    for (; j < m; ++j) {
      int s0 = __shfl(srcv, j);
      float a0 = __shfl(av, j);
      float2 x0 = *(const float2*)(nfl + (size_t)s0 * 128 + 2 * lane);
      accx = fmaf(a0, x0.x, accx); accy = fmaf(a0, x0.y, accy);
    }
  }
  *(float2*)(h + (size_t)d * 128 + 2 * lane) = make_float2(accx, accy);
}

extern "C" void kernel_launch(void* const* d_in, const int* in_sizes, int n_in,
                              void* d_out, int out_size, void* d_ws, size_t ws_size,
                              hipStream_t stream) {
  const float* nh     = (const float*)d_in[0];
  const int*   edge_y = (const int*)d_in[1];
  const int*   ei     = (const int*)d_in[2];
  const float* W_nf   = (const float*)d_in[3];
  const float* W_attn = (const float*)d_in[4];
  const float* W_out  = (const float*)d_in[5];
  const float* b_out  = (const float*)d_in[6];
  float* out = (float*)d_out;
  const int n = in_sizes[0] / 128;
  const int e = in_sizes[1];
  const int nb = (n + 1023) / 1024;

  // workspace layout (floats)
  float* nfl   = (float*)d_ws;                         // n*128 (reused as t later)
  float* s_src = nfl + (size_t)n * 128;                // n
  float* s_dst = s_src + n;                            // n
  float* ef    = s_dst + n;                            // e
  unsigned* mkey = (unsigned*)(ef + e);                // n*NTYPES
  float* denom = (float*)(mkey + (size_t)n * NTYPES);  // n*NTYPES
  int*   deg   = (int*)(denom + (size_t)n * NTYPES);   // n
  int*   base  = deg + n;                              // n
  int*   cur   = base + n;                             // n
  int*   bsum  = cur + n;                              // 256
  int*   boff  = bsum + 256;                           // 256
  float2* rec  = (float2*)(boff + 256);                // e float2

  hipMemsetAsync(mkey, 0, (size_t)2 * n * NTYPES * sizeof(float), stream);
  hipMemsetAsync(deg, 0, (size_t)n * sizeof(int), stream);

  // 1) nfl = nh @ W_nf^T  (+ s_src, s_dst)
  k_gemm<0><<<768, 256, 0, stream>>>(nh, W_nf, 32, 0, W_attn, s_src, s_dst,
                                     nullptr, nullptr, nfl, n);
  // 2) edge logits + segment max + deg histogram
  k_edge_max<<<(e + 255) / 256, 256, 0, stream>>>(ei, edge_y, s_src, s_dst, ef, mkey, deg, e);
  // 3) exp + segment sum
  k_edge_den<<<(e + 255) / 256, 256, 0, stream>>>(ei, edge_y, ef, mkey, denom, e);
  // 4) exclusive scan deg -> base, cur
  k_scan1<<<nb, 256, 0, stream>>>(deg, base, bsum, n);
  k_scan2<<<1, 256, 0, stream>>>(bsum, boff, nb);
  k_scan3<<<(n + 255) / 256, 256, 0, stream>>>(base, boff, cur, n);
  // 5) pack (src, alpha) per dst
  k_fill<<<(e + 255) / 256, 256, 0, stream>>>(ei, edge_y, ef, denom, cur, rec, e);
  // 6) h (in d_out) = gather-aggregate
  k_aggregate<<<(n + 3) / 4, 256, 0, stream>>>(rec, base, deg, nfl, out, n);
  // 7) t = b + h @ Wo2^T   (t reuses nfl region; W_out cols 128..255)
  k_gemm<1><<<768, 256, 0, stream>>>(out, W_out, 64, 32, nullptr, nullptr, nullptr,
                                     b_out, nullptr, nfl, n);
  // 8) out = relu(t + nh @ Wo1^T)
  k_gemm<2><<<768, 256, 0, stream>>>(nh, W_out, 64, 0, nullptr, nullptr, nullptr,
                                     nullptr, nfl, out, n);
}

// Round 4
// 246.928 us; speedup vs baseline: 3.1811x; 1.4666x over previous
//
#include <hip/hip_runtime.h>

#define NTYPES 5

typedef _Float16 half8 __attribute__((ext_vector_type(8)));
typedef _Float16 half4v __attribute__((ext_vector_type(4)));
typedef float float4v __attribute__((ext_vector_type(4)));

// stage rows x 128 f32 tile -> f16 LDS, row stride 256 B, swizzle byte ^= (row&7)<<4
__device__ __forceinline__ void stage_f32(
    _Float16* lds, const float* __restrict__ g, int rows, int stride4, int off4,
    int grow0, int nmax, int t)
{
  const float4* g4 = (const float4*)g;
  for (int i = t; i < rows * 32; i += 256) {
    int row = i >> 5, q = i & 31;
    float4 v = make_float4(0.f, 0.f, 0.f, 0.f);
    int gr = grow0 + row;
    if (gr < nmax) v = g4[(size_t)gr * stride4 + off4 + q];
    half4v hv = { (_Float16)v.x, (_Float16)v.y, (_Float16)v.z, (_Float16)v.w };
    int byte = row * 256 + ((q * 8) ^ ((row & 7) << 4));
    *(half4v*)((char*)lds + byte) = hv;
  }
}

// stage rows x 128 f16 tile -> f16 LDS (same layout/swizzle)
__device__ __forceinline__ void stage_h(
    _Float16* lds, const _Float16* __restrict__ g, int rows, int grow0, int nmax, int t)
{
  for (int i = t; i < rows * 16; i += 256) {
    int row = i >> 4, q = i & 15;
    uint4 v = make_uint4(0u, 0u, 0u, 0u);
    int gr = grow0 + row;
    if (gr < nmax) v = *(const uint4*)(g + (size_t)gr * 128 + q * 8);
    int byte = row * 256 + ((q * 16) ^ ((row & 7) << 4));
    *(uint4*)((char*)lds + byte) = v;
  }
}

__device__ __forceinline__ half8 frag_ld(const _Float16* lds, int row, int khw) {
  int byte = row * 256 + ((khw * 2) ^ ((row & 7) << 4));
  return *(const half8*)((const char*)lds + byte);
}

// nfl(f16) = nh @ Wnf^T ; s_src/s_dst = nfl @ a_src/a_dst
__global__ __launch_bounds__(256) void k_gemm0(
    const float* __restrict__ nh, const float* __restrict__ Wnf,
    const float* __restrict__ Wattn,
    float* __restrict__ s_src, float* __restrict__ s_dst,
    _Float16* __restrict__ nfl, int n)
{
  __shared__ _Float16 wh[128 * 128];
  __shared__ _Float16 xh[64 * 128];
  const int t = threadIdx.x, lane = t & 63, wv = t >> 6;
  const int r16 = lane & 15, g = lane >> 4;
  stage_f32(wh, Wnf, 128, 32, 0, 0, 1 << 30, t);
  float asrc[8], adst[8];
  #pragma unroll
  for (int nf = 0; nf < 8; ++nf) {
    asrc[nf] = Wattn[nf * 16 + r16];
    adst[nf] = Wattn[128 + nf * 16 + r16];
  }
  const int nchunk = (n + 63) >> 6;
  for (int c = blockIdx.x; c < nchunk; c += gridDim.x) {
    const int base = c << 6;
    __syncthreads();
    stage_f32(xh, nh, 64, 32, 0, base, n, t);
    __syncthreads();
    float4v acc[8];
    #pragma unroll
    for (int nf = 0; nf < 8; ++nf) acc[nf] = (float4v){0.f, 0.f, 0.f, 0.f};
    #pragma unroll
    for (int s = 0; s < 4; ++s) {
      half8 a = frag_ld(xh, wv * 16 + r16, s * 32 + g * 8);
      #pragma unroll
      for (int nf = 0; nf < 8; ++nf) {
        half8 b = frag_ld(wh, nf * 16 + r16, s * 32 + g * 8);
        acc[nf] = __builtin_amdgcn_mfma_f32_16x16x32_f16(a, b, acc[nf], 0, 0, 0);
      }
    }
    #pragma unroll
    for (int rr = 0; rr < 4; ++rr) {
      int node = base + wv * 16 + g * 4 + rr;
      if (node >= n) continue;
      size_t ro = (size_t)node * 128;
      #pragma unroll
      for (int nf = 0; nf < 8; ++nf) nfl[ro + nf * 16 + r16] = (_Float16)acc[nf][rr];
    }
    float ss[4] = {0.f, 0.f, 0.f, 0.f}, sd[4] = {0.f, 0.f, 0.f, 0.f};
    #pragma unroll
    for (int nf = 0; nf < 8; ++nf)
      #pragma unroll
      for (int rr = 0; rr < 4; ++rr) {
        ss[rr] = fmaf(acc[nf][rr], asrc[nf], ss[rr]);
        sd[rr] = fmaf(acc[nf][rr], adst[nf], sd[rr]);
      }
    #pragma unroll
    for (int m = 1; m <= 8; m <<= 1)
      #pragma unroll
      for (int rr = 0; rr < 4; ++rr) {
        ss[rr] += __shfl_xor(ss[rr], m);
        sd[rr] += __shfl_xor(sd[rr], m);
      }
    if (r16 == 0) {
      #pragma unroll
      for (int rr = 0; rr < 4; ++rr) {
        int node = base + wv * 16 + g * 4 + rr;
        if (node < n) { s_src[node] = ss[rr]; s_dst[node] = sd[rr]; }
      }
    }
  }
}

// deg histogram (dst only), 4 edges/thread
__global__ __launch_bounds__(256) void k_deg(
    const int* __restrict__ dsts, int* __restrict__ deg, int e)
{
  int i = (blockIdx.x * 256 + threadIdx.x) * 4;
  if (i + 3 < e) {
    int4 v = *(const int4*)(dsts + i);
    atomicAdd(&deg[v.x], 1); atomicAdd(&deg[v.y], 1);
    atomicAdd(&deg[v.z], 1); atomicAdd(&deg[v.w], 1);
  } else {
    for (; i < e; ++i) atomicAdd(&deg[dsts[i]], 1);
  }
}

// ---- exclusive scan over deg ----
__global__ __launch_bounds__(256) void k_scan1(
    const int* __restrict__ deg, int* __restrict__ base, int* __restrict__ bsum, int n)
{
  __shared__ int ws[4];
  int t = threadIdx.x;
  int g0 = blockIdx.x * 1024 + t * 4;
  int4 v = make_int4(0, 0, 0, 0);
  if (g0 + 3 < n) v = *(const int4*)(deg + g0);
  else {
    if (g0     < n) v.x = deg[g0];
    if (g0 + 1 < n) v.y = deg[g0 + 1];
    if (g0 + 2 < n) v.z = deg[g0 + 2];
    if (g0 + 3 < n) v.w = deg[g0 + 3];
  }
  int s = v.x + v.y + v.z + v.w;
  int inc = s;
  #pragma unroll
  for (int d = 1; d < 64; d <<= 1) {
    int o = __shfl_up(inc, d);
    if ((t & 63) >= d) inc += o;
  }
  int wid = t >> 6;
  if ((t & 63) == 63) ws[wid] = inc;
  __syncthreads();
  int woff = 0;
  for (int w = 0; w < wid; ++w) woff += ws[w];
  int exc = woff + inc - s;
  if (g0 + 3 < n) {
    *(int4*)(base + g0) = make_int4(exc, exc + v.x, exc + v.x + v.y, exc + v.x + v.y + v.z);
  } else {
    if (g0     < n) base[g0]     = exc;
    if (g0 + 1 < n) base[g0 + 1] = exc + v.x;
    if (g0 + 2 < n) base[g0 + 2] = exc + v.x + v.y;
  }
  if (t == 255) bsum[blockIdx.x] = woff + inc;
}

__global__ __launch_bounds__(256) void k_scan2(
    const int* __restrict__ bsum, int* __restrict__ boff, int nb)
{
  __shared__ int ws[4];
  int t = threadIdx.x;
  int x = t < nb ? bsum[t] : 0;
  int inc = x;
  #pragma unroll
  for (int d = 1; d < 64; d <<= 1) {
    int o = __shfl_up(inc, d);
    if ((t & 63) >= d) inc += o;
  }
  int wid = t >> 6;
  if ((t & 63) == 63) ws[wid] = inc;
  __syncthreads();
  int woff = 0;
  for (int w = 0; w < wid; ++w) woff += ws[w];
  if (t < nb) boff[t] = woff + inc - x;
}

__global__ __launch_bounds__(256) void k_scan3(
    int* __restrict__ base, const int* __restrict__ boff,
    int* __restrict__ cur, int n)
{
  int i = blockIdx.x * 256 + threadIdx.x;
  if (i < n) {
    int b = base[i] + boff[i >> 10];
    base[i] = b;
    cur[i] = b;
  }
}

// pack rec = {src | type<<20, s_src[src]} into per-dst ranges
__global__ __launch_bounds__(256) void k_fill(
    const int* __restrict__ ei, const int* __restrict__ ey,
    const float* __restrict__ s_src,
    int* __restrict__ cur, float2* __restrict__ rec, int e)
{
  int i = blockIdx.x * 256 + threadIdx.x;
  if (i >= e) return;
  int s = ei[i], d = ei[e + i];
  float v = s_src[s];
  int pos = atomicAdd(&cur[d], 1);
  rec[pos] = make_float2(__int_as_float(s | (ey[i] << 20)), v);
}

// fused per-dst softmax + aggregate: 16-lane group per dst, lane owns 8 comps
__global__ __launch_bounds__(256) void k_agg(
    const float2* __restrict__ rec, const int* __restrict__ base_,
    const int* __restrict__ deg_, const float* __restrict__ s_dst,
    const _Float16* __restrict__ nfl, _Float16* __restrict__ h, int n)
{
  int d = blockIdx.x * 16 + (threadIdx.x >> 4);
  if (d >= n) return;
  const int lane = threadIdx.x & 63;
  const int l = lane & 15;
  const int bsrc0 = lane & 48;
  int b = base_[d], dg = deg_[d];
  float sdd = s_dst[d];
  float acc[8] = {0.f, 0.f, 0.f, 0.f, 0.f, 0.f, 0.f, 0.f};
  float mx[5], sm[5];

  if (dg <= 16) {
    float2 r = (l < dg) ? rec[b + l] : make_float2(0.f, -3e30f);
    int packed = __float_as_int(r.x);
    int ty = (packed >> 20) & 7;
    int srcv = packed & 0xFFFFF;
    float ef = r.y + sdd;
    ef = ef >= 0.f ? ef : 0.2f * ef;
    if (l >= dg) ef = -1e30f;
    #pragma unroll
    for (int tt = 0; tt < NTYPES; ++tt) {
      float v = (ty == tt) ? ef : -1e30f;
      v = fmaxf(v, __shfl_xor(v, 1)); v = fmaxf(v, __shfl_xor(v, 2));
      v = fmaxf(v, __shfl_xor(v, 4)); v = fmaxf(v, __shfl_xor(v, 8));
      mx[tt] = v;
    }
    float ex = (l < dg) ? __expf(ef - mx[ty]) : 0.f;
    #pragma unroll
    for (int tt = 0; tt < NTYPES; ++tt) {
      float v = (ty == tt) ? ex : 0.f;
      v += __shfl_xor(v, 1); v += __shfl_xor(v, 2);
      v += __shfl_xor(v, 4); v += __shfl_xor(v, 8);
      sm[tt] = v;
    }
    float alpha = ex / sm[ty];
    int j = 0;
    for (; j + 2 <= dg; j += 2) {
      int s0 = __shfl(srcv, bsrc0 + j), s1 = __shfl(srcv, bsrc0 + j + 1);
      float a0 = __shfl(alpha, bsrc0 + j), a1 = __shfl(alpha, bsrc0 + j + 1);
      half8 x0 = *(const half8*)(nfl + (size_t)s0 * 128 + l * 8);
      half8 x1 = *(const half8*)(nfl + (size_t)s1 * 128 + l * 8);
      #pragma unroll
      for (int k = 0; k < 8; ++k) acc[k] = fmaf(a0, (float)x0[k], acc[k]);
      #pragma unroll
      for (int k = 0; k < 8; ++k) acc[k] = fmaf(a1, (float)x1[k], acc[k]);
    }
    if (j < dg) {
      int s0 = __shfl(srcv, bsrc0 + j);
      float a0 = __shfl(alpha, bsrc0 + j);
      half8 x0 = *(const half8*)(nfl + (size_t)s0 * 128 + l * 8);
      #pragma unroll
      for (int k = 0; k < 8; ++k) acc[k] = fmaf(a0, (float)x0[k], acc[k]);
    }
  } else {
    #pragma unroll
    for (int tt = 0; tt < NTYPES; ++tt) { mx[tt] = -1e30f; sm[tt] = 0.f; }
    for (int j0 = 0; j0 < dg; j0 += 16) {
      int rem = dg - j0;
      float2 r = (l < rem) ? rec[b + j0 + l] : make_float2(0.f, -3e30f);
      int ty = (__float_as_int(r.x) >> 20) & 7;
      float ef = r.y + sdd;
      ef = ef >= 0.f ? ef : 0.2f * ef;
      if (l >= rem) ef = -1e30f;
      #pragma unroll
      for (int tt = 0; tt < NTYPES; ++tt) {
        float v = (ty == tt) ? ef : -1e30f;
        v = fmaxf(v, __shfl_xor(v, 1)); v = fmaxf(v, __shfl_xor(v, 2));
        v = fmaxf(v, __shfl_xor(v, 4)); v = fmaxf(v, __shfl_xor(v, 8));
        mx[tt] = fmaxf(mx[tt], v);
      }
    }
    for (int j0 = 0; j0 < dg; j0 += 16) {
      int rem = dg - j0;
      float2 r = (l < rem) ? rec[b + j0 + l] : make_float2(0.f, -3e30f);
      int ty = (__float_as_int(r.x) >> 20) & 7;
      float ef = r.y + sdd;
      ef = ef >= 0.f ? ef : 0.2f * ef;
      float ex = (l < rem) ? __expf(ef - mx[ty]) : 0.f;
      #pragma unroll
      for (int tt = 0; tt < NTYPES; ++tt) {
        float v = (ty == tt) ? ex : 0.f;
        v += __shfl_xor(v, 1); v += __shfl_xor(v, 2);
        v += __shfl_xor(v, 4); v += __shfl_xor(v, 8);
        sm[tt] += v;
      }
    }
    for (int j0 = 0; j0 < dg; j0 += 16) {
      int rem = dg - j0;
      float2 r = (l < rem) ? rec[b + j0 + l] : make_float2(0.f, -3e30f);
      int packed = __float_as_int(r.x);
      int ty = (packed >> 20) & 7;
      int srcv = packed & 0xFFFFF;
      float ef = r.y + sdd;
      ef = ef >= 0.f ? ef : 0.2f * ef;
      float alpha = (l < rem) ? __expf(ef - mx[ty]) / sm[ty] : 0.f;
      int jm = rem < 16 ? rem : 16;
      for (int j = 0; j < jm; ++j) {
        int s0 = __shfl(srcv, bsrc0 + j);
        float a0 = __shfl(alpha, bsrc0 + j);
        half8 x0 = *(const half8*)(nfl + (size_t)s0 * 128 + l * 8);
        #pragma unroll
        for (int k = 0; k < 8; ++k) acc[k] = fmaf(a0, (float)x0[k], acc[k]);
      }
    }
  }
  half8 hv;
  #pragma unroll
  for (int k = 0; k < 8; ++k) hv[k] = (_Float16)acc[k];
  *(half8*)(h + (size_t)d * 128 + l * 8) = hv;
}

// out = relu(b + nh @ Wo1^T + h @ Wo2^T), jhalf = blockIdx&1 owns 64 cols
__global__ __launch_bounds__(256) void k_gemmO(
    const float* __restrict__ nh, const _Float16* __restrict__ hbuf,
    const float* __restrict__ Wout, const float* __restrict__ bias,
    float* __restrict__ out, int n)
{
  __shared__ _Float16 w1[64 * 128], w2[64 * 128];
  __shared__ _Float16 x1[64 * 128], x2[64 * 128];
  const int t = threadIdx.x, lane = t & 63, wv = t >> 6;
  const int r16 = lane & 15, g = lane >> 4;
  const int jhalf = blockIdx.x & 1;
  stage_f32(w1, Wout, 64, 64, 0,  jhalf * 64, 1 << 30, t);
  stage_f32(w2, Wout, 64, 64, 32, jhalf * 64, 1 << 30, t);
  float bv[4];
  #pragma unroll
  for (int nf = 0; nf < 4; ++nf) bv[nf] = bias[jhalf * 64 + nf * 16 + r16];
  const int nchunk = (n + 63) >> 6;
  for (int c = blockIdx.x >> 1; c < nchunk; c += gridDim.x >> 1) {
    const int base = c << 6;
    __syncthreads();
    stage_f32(x1, nh, 64, 32, 0, base, n, t);
    stage_h(x2, hbuf, 64, base, n, t);
    __syncthreads();
    float4v acc[4];
    #pragma unroll
    for (int nf = 0; nf < 4; ++nf) acc[nf] = (float4v){0.f, 0.f, 0.f, 0.f};
    #pragma unroll
    for (int s = 0; s < 4; ++s) {
      half8 a1 = frag_ld(x1, wv * 16 + r16, s * 32 + g * 8);
      half8 a2 = frag_ld(x2, wv * 16 + r16, s * 32 + g * 8);
      #pragma unroll
      for (int nf = 0; nf < 4; ++nf) {
        acc[nf] = __builtin_amdgcn_mfma_f32_16x16x32_f16(a1, frag_ld(w1, nf * 16 + r16, s * 32 + g * 8), acc[nf], 0, 0, 0);
        acc[nf] = __builtin_amdgcn_mfma_f32_16x16x32_f16(a2, frag_ld(w2, nf * 16 + r16, s * 32 + g * 8), acc[nf], 0, 0, 0);
      }
    }
    #pragma unroll
    for (int rr = 0; rr < 4; ++rr) {
      int node = base + wv * 16 + g * 4 + rr;
      if (node >= n) continue;
      #pragma unroll
      for (int nf = 0; nf < 4; ++nf)
        out[(size_t)node * 128 + jhalf * 64 + nf * 16 + r16] = fmaxf(acc[nf][rr] + bv[nf], 0.f);
    }
  }
}

extern "C" void kernel_launch(void* const* d_in, const int* in_sizes, int n_in,
                              void* d_out, int out_size, void* d_ws, size_t ws_size,
                              hipStream_t stream) {
  const float* nh     = (const float*)d_in[0];
  const int*   edge_y = (const int*)d_in[1];
  const int*   ei     = (const int*)d_in[2];
  const float* W_nf   = (const float*)d_in[3];
  const float* W_attn = (const float*)d_in[4];
  const float* W_out  = (const float*)d_in[5];
  const float* b_out  = (const float*)d_in[6];
  float* out = (float*)d_out;
  const int n = in_sizes[0] / 128;
  const int e = in_sizes[1];
  const int nb = (n + 1023) / 1024;

  // workspace layout
  _Float16* nfl_h = (_Float16*)d_ws;                   // n*128 f16
  _Float16* h_h   = nfl_h + (size_t)n * 128;           // n*128 f16
  float* s_src = (float*)(h_h + (size_t)n * 128);      // n
  float* s_dst = s_src + n;                            // n
  int*   deg   = (int*)(s_dst + n);                    // n
  int*   base_ = deg + n;                              // n
  int*   cur   = base_ + n;                            // n
  int*   bsum  = cur + n;                              // 256
  int*   boff  = bsum + 256;                           // 256
  float2* rec  = (float2*)(boff + 256);                // e float2

  hipMemsetAsync(deg, 0, (size_t)n * sizeof(int), stream);

  // 1) nfl(f16) = nh @ W_nf^T ; s_src/s_dst
  k_gemm0<<<768, 256, 0, stream>>>(nh, W_nf, W_attn, s_src, s_dst, nfl_h, n);
  // 2) deg histogram
  k_deg<<<(e / 4 + 255) / 256, 256, 0, stream>>>(ei + e, deg, e);
  // 3) exclusive scan deg -> base, cur
  k_scan1<<<nb, 256, 0, stream>>>(deg, base_, bsum, n);
  k_scan2<<<1, 256, 0, stream>>>(bsum, boff, nb);
  k_scan3<<<(n + 255) / 256, 256, 0, stream>>>(base_, boff, cur, n);
  // 4) pack rec per dst
  k_fill<<<(e + 255) / 256, 256, 0, stream>>>(ei, edge_y, s_src, cur, rec, e);
  // 5) fused per-dst softmax + aggregate -> h (f16)
  k_agg<<<(n + 15) / 16, 256, 0, stream>>>(rec, base_, deg, s_dst, nfl_h, h_h, n);
  // 6) out = relu(b + nh@Wo1^T + h@Wo2^T)
  k_gemmO<<<1024, 256, 0, stream>>>(nh, h_h, W_out, b_out, out, n);
}

// Round 5
// 217.962 us; speedup vs baseline: 3.6039x; 1.1329x over previous
//
#include <hip/hip_runtime.h>

#define NTYPES 5
#define EPB 16384     // edges per hist/scatter block
#define CAP 6144      // max edges per 256-dst bucket handled in LDS (avg 2560)

typedef _Float16 half8 __attribute__((ext_vector_type(8)));
typedef _Float16 half4v __attribute__((ext_vector_type(4)));
typedef float float4v __attribute__((ext_vector_type(4)));

// stage rows x 128 f32 tile -> f16 LDS, row stride 256 B, swizzle byte ^= (row&7)<<4
__device__ __forceinline__ void stage_f32(
    _Float16* lds, const float* __restrict__ g, int rows, int stride4, int off4,
    int grow0, int nmax, int t)
{
  const float4* g4 = (const float4*)g;
  for (int i = t; i < rows * 32; i += 256) {
    int row = i >> 5, q = i & 31;
    float4 v = make_float4(0.f, 0.f, 0.f, 0.f);
    int gr = grow0 + row;
    if (gr < nmax) v = g4[(size_t)gr * stride4 + off4 + q];
    half4v hv = { (_Float16)v.x, (_Float16)v.y, (_Float16)v.z, (_Float16)v.w };
    int byte = row * 256 + ((q * 8) ^ ((row & 7) << 4));
    *(half4v*)((char*)lds + byte) = hv;
  }
}

// stage rows x 128 f16 tile -> f16 LDS (same layout/swizzle)
__device__ __forceinline__ void stage_h(
    _Float16* lds, const _Float16* __restrict__ g, int rows, int grow0, int nmax, int t)
{
  for (int i = t; i < rows * 16; i += 256) {
    int row = i >> 4, q = i & 15;
    uint4 v = make_uint4(0u, 0u, 0u, 0u);
    int gr = grow0 + row;
    if (gr < nmax) v = *(const uint4*)(g + (size_t)gr * 128 + q * 8);
    int byte = row * 256 + ((q * 16) ^ ((row & 7) << 4));
    *(uint4*)((char*)lds + byte) = v;
  }
}

__device__ __forceinline__ half8 frag_ld(const _Float16* lds, int row, int khw) {
  int byte = row * 256 + ((khw * 2) ^ ((row & 7) << 4));
  return *(const half8*)((const char*)lds + byte);
}

// nfl(f16) = nh @ Wnf^T ; s_src/s_dst = nfl @ a_src/a_dst
__global__ __launch_bounds__(256) void k_gemm0(
    const float* __restrict__ nh, const float* __restrict__ Wnf,
    const float* __restrict__ Wattn,
    float* __restrict__ s_src, float* __restrict__ s_dst,
    _Float16* __restrict__ nfl, int n)
{
  __shared__ _Float16 wh[128 * 128];
  __shared__ _Float16 xh[64 * 128];
  const int t = threadIdx.x, lane = t & 63, wv = t >> 6;
  const int r16 = lane & 15, g = lane >> 4;
  stage_f32(wh, Wnf, 128, 32, 0, 0, 1 << 30, t);
  float asrc[8], adst[8];
  #pragma unroll
  for (int nf = 0; nf < 8; ++nf) {
    asrc[nf] = Wattn[nf * 16 + r16];
    adst[nf] = Wattn[128 + nf * 16 + r16];
  }
  const int nchunk = (n + 63) >> 6;
  for (int c = blockIdx.x; c < nchunk; c += gridDim.x) {
    const int base = c << 6;
    __syncthreads();
    stage_f32(xh, nh, 64, 32, 0, base, n, t);
    __syncthreads();
    float4v acc[8];
    #pragma unroll
    for (int nf = 0; nf < 8; ++nf) acc[nf] = (float4v){0.f, 0.f, 0.f, 0.f};
    #pragma unroll
    for (int s = 0; s < 4; ++s) {
      half8 a = frag_ld(xh, wv * 16 + r16, s * 32 + g * 8);
      #pragma unroll
      for (int nf = 0; nf < 8; ++nf) {
        half8 b = frag_ld(wh, nf * 16 + r16, s * 32 + g * 8);
        acc[nf] = __builtin_amdgcn_mfma_f32_16x16x32_f16(a, b, acc[nf], 0, 0, 0);
      }
    }
    #pragma unroll
    for (int rr = 0; rr < 4; ++rr) {
      int node = base + wv * 16 + g * 4 + rr;
      if (node >= n) continue;
      size_t ro = (size_t)node * 128;
      #pragma unroll
      for (int nf = 0; nf < 8; ++nf) nfl[ro + nf * 16 + r16] = (_Float16)acc[nf][rr];
    }
    float ss[4] = {0.f, 0.f, 0.f, 0.f}, sd[4] = {0.f, 0.f, 0.f, 0.f};
    #pragma unroll
    for (int nf = 0; nf < 8; ++nf)
      #pragma unroll
      for (int rr = 0; rr < 4; ++rr) {
        ss[rr] = fmaf(acc[nf][rr], asrc[nf], ss[rr]);
        sd[rr] = fmaf(acc[nf][rr], adst[nf], sd[rr]);
      }
    #pragma unroll
    for (int m = 1; m <= 8; m <<= 1)
      #pragma unroll
      for (int rr = 0; rr < 4; ++rr) {
        ss[rr] += __shfl_xor(ss[rr], m);
        sd[rr] += __shfl_xor(sd[rr], m);
      }
    if (r16 == 0) {
      #pragma unroll
      for (int rr = 0; rr < 4; ++rr) {
        int node = base + wv * 16 + g * 4 + rr;
        if (node < n) { s_src[node] = ss[rr]; s_dst[node] = sd[rr]; }
      }
    }
  }
}

// per-block bucket histogram (bucket = dst >> 8), LDS atomics only
__global__ __launch_bounds__(256) void k_hist(
    const int* __restrict__ dsts, int* __restrict__ cnt, int e, int nbk, int nblk)
{
  __shared__ int hist[1024];
  const int t = threadIdx.x, b = blockIdx.x;
  for (int k = t; k < nbk; k += 256) hist[k] = 0;
  __syncthreads();
  const int i0 = b * EPB;
  const int iend = min(i0 + EPB, e);
  for (int i = i0 + t; i < iend; i += 256)
    atomicAdd(&hist[dsts[i] >> 8], 1);
  __syncthreads();
  for (int k = t; k < nbk; k += 256) cnt[k * nblk + b] = hist[k];
}

// ---- exclusive scan (in-place capable) ----
__global__ __launch_bounds__(256) void k_scan1(
    const int* __restrict__ deg, int* __restrict__ base, int* __restrict__ bsum, int n)
{
  __shared__ int ws[4];
  int t = threadIdx.x;
  int g0 = blockIdx.x * 1024 + t * 4;
  int4 v = make_int4(0, 0, 0, 0);
  if (g0 + 3 < n) v = *(const int4*)(deg + g0);
  else {
    if (g0     < n) v.x = deg[g0];
    if (g0 + 1 < n) v.y = deg[g0 + 1];
    if (g0 + 2 < n) v.z = deg[g0 + 2];
    if (g0 + 3 < n) v.w = deg[g0 + 3];
  }
  int s = v.x + v.y + v.z + v.w;
  int inc = s;
  #pragma unroll
  for (int d = 1; d < 64; d <<= 1) {
    int o = __shfl_up(inc, d);
    if ((t & 63) >= d) inc += o;
  }
  int wid = t >> 6;
  if ((t & 63) == 63) ws[wid] = inc;
  __syncthreads();
  int woff = 0;
  for (int w = 0; w < wid; ++w) woff += ws[w];
  int exc = woff + inc - s;
  if (g0 + 3 < n) {
    *(int4*)(base + g0) = make_int4(exc, exc + v.x, exc + v.x + v.y, exc + v.x + v.y + v.z);
  } else {
    if (g0     < n) base[g0]     = exc;
    if (g0 + 1 < n) base[g0 + 1] = exc + v.x;
    if (g0 + 2 < n) base[g0 + 2] = exc + v.x + v.y;
  }
  if (t == 255) bsum[blockIdx.x] = woff + inc;
}

__global__ __launch_bounds__(256) void k_scan2(
    const int* __restrict__ bsum, int* __restrict__ boff, int nb)
{
  __shared__ int ws[4];
  int t = threadIdx.x;
  int x = t < nb ? bsum[t] : 0;
  int inc = x;
  #pragma unroll
  for (int d = 1; d < 64; d <<= 1) {
    int o = __shfl_up(inc, d);
    if ((t & 63) >= d) inc += o;
  }
  int wid = t >> 6;
  if ((t & 63) == 63) ws[wid] = inc;
  __syncthreads();
  int woff = 0;
  for (int w = 0; w < wid; ++w) woff += ws[w];
  if (t < nb) boff[t] = woff + inc - x;
}

__global__ __launch_bounds__(256) void k_scan3(
    int* __restrict__ base, const int* __restrict__ boff, int n)
{
  int i = blockIdx.x * 256 + threadIdx.x;
  if (i < n) base[i] += boff[i >> 10];
}

// bucket-grouped scatter: payload = src | ty<<17 | (d&255)<<20, LDS cursors
__global__ __launch_bounds__(256) void k_scatter2(
    const int* __restrict__ ei, const int* __restrict__ ey,
    const int* __restrict__ cnt_s, unsigned* __restrict__ rec,
    int e, int nbk, int nblk)
{
  __shared__ int cur[1024];
  const int t = threadIdx.x, b = blockIdx.x;
  for (int k = t; k < nbk; k += 256) cur[k] = cnt_s[k * nblk + b];
  __syncthreads();
  const int i0 = b * EPB;
  const int iend = min(i0 + EPB, e);
  for (int i = i0 + t; i < iend; i += 256) {
    int s = ei[i], d = ei[e + i], ty = ey[i];
    int pos = atomicAdd(&cur[d >> 8], 1);
    rec[pos] = (unsigned)s | ((unsigned)ty << 17) | ((unsigned)(d & 255) << 20);
  }
}

// one block per bucket: LDS CSR build + per-dst softmax + gather aggregate
__global__ __launch_bounds__(256) void k_agg2(
    const unsigned* __restrict__ rec, const int* __restrict__ cnt_s,
    const float* __restrict__ s_src, const float* __restrict__ s_dst,
    const _Float16* __restrict__ nfl, _Float16* __restrict__ h,
    int n, int e, int nbk, int nblk)
{
  __shared__ unsigned ord[CAP];
  __shared__ float efl[CAP];
  __shared__ int dcnt[256];
  __shared__ int dbase[257];
  __shared__ float sdl[256];
  __shared__ int wsum[4];
  const int t = threadIdx.x;
  const int k = blockIdx.x;
  const int d0 = k << 8;
  const int ndst = min(256, n - d0);
  const int bs = cnt_s[k * nblk];
  const int be = (k + 1 < nbk) ? cnt_s[(k + 1) * nblk] : e;
  const int cnt = be - bs;
  dcnt[t] = 0;
  if (t < ndst) sdl[t] = s_dst[d0 + t];
  __syncthreads();
  const int g = t >> 4, l = t & 15;

  if (cnt <= CAP) {
    for (int i = t; i < cnt; i += 256)
      atomicAdd(&dcnt[(rec[bs + i] >> 20) & 255], 1);
    __syncthreads();
    {  // exclusive scan dcnt -> dbase (also seed dcnt as cursor)
      int v = dcnt[t];
      int inc = v;
      #pragma unroll
      for (int dd = 1; dd < 64; dd <<= 1) {
        int o = __shfl_up(inc, dd);
        if ((t & 63) >= dd) inc += o;
      }
      int wid = t >> 6;
      if ((t & 63) == 63) wsum[wid] = inc;
      __syncthreads();
      int woff = 0;
      for (int w = 0; w < wid; ++w) woff += wsum[w];
      dbase[t] = woff + inc - v;
      dcnt[t]  = woff + inc - v;
      if (t == 255) dbase[256] = woff + inc;
    }
    __syncthreads();
    for (int i = t; i < cnt; i += 256) {
      unsigned p = rec[bs + i];
      int pos = atomicAdd(&dcnt[(p >> 20) & 255], 1);
      ord[pos] = p;
    }
    __syncthreads();
    for (int i = t; i < cnt; i += 256) {
      unsigned p = ord[i];
      float ef = s_src[p & 0x1FFFF] + sdl[(p >> 20) & 255];
      efl[i] = ef >= 0.f ? ef : 0.2f * ef;
    }
    __syncthreads();
    for (int di = g; di < ndst; di += 16) {
      int s0 = dbase[di], deg = dbase[di + 1] - s0;
      float acc[8] = {0.f, 0.f, 0.f, 0.f, 0.f, 0.f, 0.f, 0.f};
      if (deg > 0) {
        float mx[NTYPES];
        #pragma unroll
        for (int tt = 0; tt < NTYPES; ++tt) mx[tt] = -1e30f;
        for (int j0 = 0; j0 < deg; j0 += 16) {
          int jj = j0 + l;
          bool ok = jj < deg;
          float ef = ok ? efl[s0 + jj] : -1e30f;
          int ty = ok ? (int)((ord[s0 + jj] >> 17) & 7) : 7;
          #pragma unroll
          for (int tt = 0; tt < NTYPES; ++tt) {
            float v = (ty == tt) ? ef : -1e30f;
            v = fmaxf(v, __shfl_xor(v, 1)); v = fmaxf(v, __shfl_xor(v, 2));
            v = fmaxf(v, __shfl_xor(v, 4)); v = fmaxf(v, __shfl_xor(v, 8));
            mx[tt] = fmaxf(mx[tt], v);
          }
        }
        float sm[NTYPES];
        #pragma unroll
        for (int tt = 0; tt < NTYPES; ++tt) sm[tt] = 0.f;
        for (int j0 = 0; j0 < deg; j0 += 16) {
          int jj = j0 + l;
          bool ok = jj < deg;
          int ty = ok ? (int)((ord[s0 + jj] >> 17) & 7) : 7;
          float ex = ok ? __expf(efl[s0 + jj] - mx[ty]) : 0.f;
          if (ok) efl[s0 + jj] = ex;
          #pragma unroll
          for (int tt = 0; tt < NTYPES; ++tt) {
            float v = (ty == tt) ? ex : 0.f;
            v += __shfl_xor(v, 1); v += __shfl_xor(v, 2);
            v += __shfl_xor(v, 4); v += __shfl_xor(v, 8);
            sm[tt] += v;
          }
        }
        float rsm[NTYPES];
        #pragma unroll
        for (int tt = 0; tt < NTYPES; ++tt) rsm[tt] = sm[tt] > 0.f ? 1.f / sm[tt] : 0.f;
        int j = 0;
        for (; j + 2 <= deg; j += 2) {
          unsigned p0 = ord[s0 + j], p1 = ord[s0 + j + 1];
          float a0 = efl[s0 + j] * rsm[(p0 >> 17) & 7];
          float a1 = efl[s0 + j + 1] * rsm[(p1 >> 17) & 7];
          half8 x0 = *(const half8*)(nfl + (size_t)(p0 & 0x1FFFF) * 128 + l * 8);
          half8 x1 = *(const half8*)(nfl + (size_t)(p1 & 0x1FFFF) * 128 + l * 8);
          #pragma unroll
          for (int kk = 0; kk < 8; ++kk) acc[kk] = fmaf(a0, (float)x0[kk], acc[kk]);
          #pragma unroll
          for (int kk = 0; kk < 8; ++kk) acc[kk] = fmaf(a1, (float)x1[kk], acc[kk]);
        }
        if (j < deg) {
          unsigned p0 = ord[s0 + j];
          float a0 = efl[s0 + j] * rsm[(p0 >> 17) & 7];
          half8 x0 = *(const half8*)(nfl + (size_t)(p0 & 0x1FFFF) * 128 + l * 8);
          #pragma unroll
          for (int kk = 0; kk < 8; ++kk) acc[kk] = fmaf(a0, (float)x0[kk], acc[kk]);
        }
      }
      half8 hv;
      #pragma unroll
      for (int kk = 0; kk < 8; ++kk) hv[kk] = (_Float16)acc[kk];
      *(half8*)(h + (size_t)(d0 + di) * 128 + l * 8) = hv;
    }
  } else {
    // fallback (bucket overflow — not expected): stream global rec per dst
    const int gb = (t & 63) & 48;
    for (int di = g; di < ndst; di += 16) {
      float mx[NTYPES], sm[NTYPES];
      #pragma unroll
      for (int tt = 0; tt < NTYPES; ++tt) { mx[tt] = -1e30f; sm[tt] = 0.f; }
      for (int j0 = 0; j0 < cnt; j0 += 16) {
        int jj = j0 + l;
        unsigned p = (jj < cnt) ? rec[bs + jj] : 0xFFFFFFFFu;
        bool mine = (p != 0xFFFFFFFFu) && (int)((p >> 20) & 255) == di;
        float ef = -1e30f; int ty = 7;
        if (mine) {
          ef = s_src[p & 0x1FFFF] + sdl[di];
          ef = ef >= 0.f ? ef : 0.2f * ef;
          ty = (p >> 17) & 7;
        }
        #pragma unroll
        for (int tt = 0; tt < NTYPES; ++tt) {
          float v = (mine && ty == tt) ? ef : -1e30f;
          v = fmaxf(v, __shfl_xor(v, 1)); v = fmaxf(v, __shfl_xor(v, 2));
          v = fmaxf(v, __shfl_xor(v, 4)); v = fmaxf(v, __shfl_xor(v, 8));
          mx[tt] = fmaxf(mx[tt], v);
        }
      }
      for (int j0 = 0; j0 < cnt; j0 += 16) {
        int jj = j0 + l;
        unsigned p = (jj < cnt) ? rec[bs + jj] : 0xFFFFFFFFu;
        bool mine = (p != 0xFFFFFFFFu) && (int)((p >> 20) & 255) == di;
        float ex = 0.f; int ty = 7;
        if (mine) {
          float ef = s_src[p & 0x1FFFF] + sdl[di];
          ef = ef >= 0.f ? ef : 0.2f * ef;
          ty = (p >> 17) & 7;
          ex = __expf(ef - mx[ty]);
        }
        #pragma unroll
        for (int tt = 0; tt < NTYPES; ++tt) {
          float v = (ty == tt) ? ex : 0.f;
          v += __shfl_xor(v, 1); v += __shfl_xor(v, 2);
          v += __shfl_xor(v, 4); v += __shfl_xor(v, 8);
          sm[tt] += v;
        }
      }
      float rsm[NTYPES];
      #pragma unroll
      for (int tt = 0; tt < NTYPES; ++tt) rsm[tt] = sm[tt] > 0.f ? 1.f / sm[tt] : 0.f;
      float acc[8] = {0.f, 0.f, 0.f, 0.f, 0.f, 0.f, 0.f, 0.f};
      for (int j0 = 0; j0 < cnt; j0 += 16) {
        int jj = j0 + l;
        unsigned p = (jj < cnt) ? rec[bs + jj] : 0xFFFFFFFFu;
        bool mine = (p != 0xFFFFFFFFu) && (int)((p >> 20) & 255) == di;
        float al = 0.f;
        if (mine) {
          float ef = s_src[p & 0x1FFFF] + sdl[di];
          ef = ef >= 0.f ? ef : 0.2f * ef;
          int ty = (p >> 17) & 7;
          al = __expf(ef - mx[ty]) * rsm[ty];
        }
        unsigned pv = mine ? p : 0xFFFFFFFFu;
        for (int jj2 = 0; jj2 < 16; ++jj2) {
          unsigned pp = __shfl(pv, gb + jj2);
          float aa = __shfl(al, gb + jj2);
          if (pp != 0xFFFFFFFFu) {
            half8 x = *(const half8*)(nfl + (size_t)(pp & 0x1FFFF) * 128 + l * 8);
            #pragma unroll
            for (int kk = 0; kk < 8; ++kk) acc[kk] = fmaf(aa, (float)x[kk], acc[kk]);
          }
        }
      }
      half8 hv;
      #pragma unroll
      for (int kk = 0; kk < 8; ++kk) hv[kk] = (_Float16)acc[kk];
      *(half8*)(h + (size_t)(d0 + di) * 128 + l * 8) = hv;
    }
  }
}

// out = relu(b + nh @ Wo1^T + h @ Wo2^T), jhalf = blockIdx&1 owns 64 cols
__global__ __launch_bounds__(256) void k_gemmO(
    const float* __restrict__ nh, const _Float16* __restrict__ hbuf,
    const float* __restrict__ Wout, const float* __restrict__ bias,
    float* __restrict__ out, int n)
{
  __shared__ _Float16 w1[64 * 128], w2[64 * 128];
  __shared__ _Float16 x1[64 * 128], x2[64 * 128];
  const int t = threadIdx.x, lane = t & 63, wv = t >> 6;
  const int r16 = lane & 15, g = lane >> 4;
  const int jhalf = blockIdx.x & 1;
  stage_f32(w1, Wout, 64, 64, 0,  jhalf * 64, 1 << 30, t);
  stage_f32(w2, Wout, 64, 64, 32, jhalf * 64, 1 << 30, t);
  float bv[4];
  #pragma unroll
  for (int nf = 0; nf < 4; ++nf) bv[nf] = bias[jhalf * 64 + nf * 16 + r16];
  const int nchunk = (n + 63) >> 6;
  for (int c = blockIdx.x >> 1; c < nchunk; c += gridDim.x >> 1) {
    const int base = c << 6;
    __syncthreads();
    stage_f32(x1, nh, 64, 32, 0, base, n, t);
    stage_h(x2, hbuf, 64, base, n, t);
    __syncthreads();
    float4v acc[4];
    #pragma unroll
    for (int nf = 0; nf < 4; ++nf) acc[nf] = (float4v){0.f, 0.f, 0.f, 0.f};
    #pragma unroll
    for (int s = 0; s < 4; ++s) {
      half8 a1 = frag_ld(x1, wv * 16 + r16, s * 32 + g * 8);
      half8 a2 = frag_ld(x2, wv * 16 + r16, s * 32 + g * 8);
      #pragma unroll
      for (int nf = 0; nf < 4; ++nf) {
        acc[nf] = __builtin_amdgcn_mfma_f32_16x16x32_f16(a1, frag_ld(w1, nf * 16 + r16, s * 32 + g * 8), acc[nf], 0, 0, 0);
        acc[nf] = __builtin_amdgcn_mfma_f32_16x16x32_f16(a2, frag_ld(w2, nf * 16 + r16, s * 32 + g * 8), acc[nf], 0, 0, 0);
      }
    }
    #pragma unroll
    for (int rr = 0; rr < 4; ++rr) {
      int node = base + wv * 16 + g * 4 + rr;
      if (node >= n) continue;
      #pragma unroll
      for (int nf = 0; nf < 4; ++nf)
        out[(size_t)node * 128 + jhalf * 64 + nf * 16 + r16] = fmaxf(acc[nf][rr] + bv[nf], 0.f);
    }
  }
}

extern "C" void kernel_launch(void* const* d_in, const int* in_sizes, int n_in,
                              void* d_out, int out_size, void* d_ws, size_t ws_size,
                              hipStream_t stream) {
  const float* nh     = (const float*)d_in[0];
  const int*   edge_y = (const int*)d_in[1];
  const int*   ei     = (const int*)d_in[2];
  const float* W_nf   = (const float*)d_in[3];
  const float* W_attn = (const float*)d_in[4];
  const float* W_out  = (const float*)d_in[5];
  const float* b_out  = (const float*)d_in[6];
  float* out = (float*)d_out;
  const int n = in_sizes[0] / 128;
  const int e = in_sizes[1];
  const int nbk  = (n + 255) >> 8;          // buckets of 256 dsts
  const int nblk = (e + EPB - 1) / EPB;     // hist/scatter blocks
  const int ncnt = nbk * nblk;
  const int nb2  = (ncnt + 1023) / 1024;

  // workspace layout
  _Float16* nfl_h = (_Float16*)d_ws;                   // n*128 f16
  _Float16* h_h   = nfl_h + (size_t)n * 128;           // n*128 f16
  float* s_src = (float*)(h_h + (size_t)n * 128);      // n
  float* s_dst = s_src + n;                            // n
  int*   cnt   = (int*)(s_dst + n);                    // nbk*nblk
  int*   bsum  = cnt + ncnt;                           // 256
  int*   boff  = bsum + 256;                           // 256
  unsigned* rec = (unsigned*)(boff + 256);             // e

  // 1) nfl(f16) = nh @ W_nf^T ; s_src/s_dst
  k_gemm0<<<768, 256, 0, stream>>>(nh, W_nf, W_attn, s_src, s_dst, nfl_h, n);
  // 2) bucket histogram + scan (in-place)
  k_hist<<<nblk, 256, 0, stream>>>(ei + e, cnt, e, nbk, nblk);
  k_scan1<<<nb2, 256, 0, stream>>>(cnt, cnt, bsum, ncnt);
  k_scan2<<<1, 256, 0, stream>>>(bsum, boff, nb2);
  k_scan3<<<(ncnt + 255) / 256, 256, 0, stream>>>(cnt, boff, ncnt);
  // 3) bucket-grouped scatter (4B payload, contiguous segments)
  k_scatter2<<<nblk, 256, 0, stream>>>(ei, edge_y, cnt, rec, e, nbk, nblk);
  // 4) per-bucket LDS CSR + softmax + aggregate -> h (f16)
  k_agg2<<<nbk, 256, 0, stream>>>(rec, cnt, s_src, s_dst, nfl_h, h_h, n, e, nbk, nblk);
  // 5) out = relu(b + nh@Wo1^T + h@Wo2^T)
  k_gemmO<<<1024, 256, 0, stream>>>(nh, h_h, W_out, b_out, out, n);
}

// Round 6
// 179.492 us; speedup vs baseline: 4.3763x; 1.2143x over previous
//
#include <hip/hip_runtime.h>

#define NTYPES 5
#define EPB 16384     // edges per hist/scatter block
#define BKSH 6        // 64 dsts per bucket
#define BKDST 64
#define CAP 2048      // max edges per bucket in LDS (avg 640, Poisson std ~25)

typedef _Float16 half8 __attribute__((ext_vector_type(8)));
typedef _Float16 half4v __attribute__((ext_vector_type(4)));
typedef float float4v __attribute__((ext_vector_type(4)));

// stage rows x 128 f32 tile -> f16 LDS, row stride 256 B, swizzle byte ^= (row&7)<<4
__device__ __forceinline__ void stage_f32(
    _Float16* lds, const float* __restrict__ g, int rows, int stride4, int off4,
    int grow0, int nmax, int t)
{
  const float4* g4 = (const float4*)g;
  for (int i = t; i < rows * 32; i += 256) {
    int row = i >> 5, q = i & 31;
    float4 v = make_float4(0.f, 0.f, 0.f, 0.f);
    int gr = grow0 + row;
    if (gr < nmax) v = g4[(size_t)gr * stride4 + off4 + q];
    half4v hv = { (_Float16)v.x, (_Float16)v.y, (_Float16)v.z, (_Float16)v.w };
    int byte = row * 256 + ((q * 8) ^ ((row & 7) << 4));
    *(half4v*)((char*)lds + byte) = hv;
  }
}

// stage rows x 128 f16 tile -> f16 LDS (same layout/swizzle)
__device__ __forceinline__ void stage_h(
    _Float16* lds, const _Float16* __restrict__ g, int rows, int grow0, int nmax, int t)
{
  for (int i = t; i < rows * 16; i += 256) {
    int row = i >> 4, q = i & 15;
    uint4 v = make_uint4(0u, 0u, 0u, 0u);
    int gr = grow0 + row;
    if (gr < nmax) v = *(const uint4*)(g + (size_t)gr * 128 + q * 8);
    int byte = row * 256 + ((q * 16) ^ ((row & 7) << 4));
    *(uint4*)((char*)lds + byte) = v;
  }
}

__device__ __forceinline__ half8 frag_ld(const _Float16* lds, int row, int khw) {
  int byte = row * 256 + ((khw * 2) ^ ((row & 7) << 4));
  return *(const half8*)((const char*)lds + byte);
}

// nfl(f16) = nh @ Wnf^T ; s_src/s_dst = nfl @ a_src/a_dst
__global__ __launch_bounds__(256) void k_gemm0(
    const float* __restrict__ nh, const float* __restrict__ Wnf,
    const float* __restrict__ Wattn,
    float* __restrict__ s_src, float* __restrict__ s_dst,
    _Float16* __restrict__ nfl, int n)
{
  __shared__ _Float16 wh[128 * 128];
  __shared__ _Float16 xh[64 * 128];
  const int t = threadIdx.x, lane = t & 63, wv = t >> 6;
  const int r16 = lane & 15, g = lane >> 4;
  stage_f32(wh, Wnf, 128, 32, 0, 0, 1 << 30, t);
  float asrc[8], adst[8];
  #pragma unroll
  for (int nf = 0; nf < 8; ++nf) {
    asrc[nf] = Wattn[nf * 16 + r16];
    adst[nf] = Wattn[128 + nf * 16 + r16];
  }
  const int nchunk = (n + 63) >> 6;
  for (int c = blockIdx.x; c < nchunk; c += gridDim.x) {
    const int base = c << 6;
    __syncthreads();
    stage_f32(xh, nh, 64, 32, 0, base, n, t);
    __syncthreads();
    float4v acc[8];
    #pragma unroll
    for (int nf = 0; nf < 8; ++nf) acc[nf] = (float4v){0.f, 0.f, 0.f, 0.f};
    #pragma unroll
    for (int s = 0; s < 4; ++s) {
      half8 a = frag_ld(xh, wv * 16 + r16, s * 32 + g * 8);
      #pragma unroll
      for (int nf = 0; nf < 8; ++nf) {
        half8 b = frag_ld(wh, nf * 16 + r16, s * 32 + g * 8);
        acc[nf] = __builtin_amdgcn_mfma_f32_16x16x32_f16(a, b, acc[nf], 0, 0, 0);
      }
    }
    #pragma unroll
    for (int rr = 0; rr < 4; ++rr) {
      int node = base + wv * 16 + g * 4 + rr;
      if (node >= n) continue;
      size_t ro = (size_t)node * 128;
      #pragma unroll
      for (int nf = 0; nf < 8; ++nf) nfl[ro + nf * 16 + r16] = (_Float16)acc[nf][rr];
    }
    float ss[4] = {0.f, 0.f, 0.f, 0.f}, sd[4] = {0.f, 0.f, 0.f, 0.f};
    #pragma unroll
    for (int nf = 0; nf < 8; ++nf)
      #pragma unroll
      for (int rr = 0; rr < 4; ++rr) {
        ss[rr] = fmaf(acc[nf][rr], asrc[nf], ss[rr]);
        sd[rr] = fmaf(acc[nf][rr], adst[nf], sd[rr]);
      }
    #pragma unroll
    for (int m = 1; m <= 8; m <<= 1)
      #pragma unroll
      for (int rr = 0; rr < 4; ++rr) {
        ss[rr] += __shfl_xor(ss[rr], m);
        sd[rr] += __shfl_xor(sd[rr], m);
      }
    if (r16 == 0) {
      #pragma unroll
      for (int rr = 0; rr < 4; ++rr) {
        int node = base + wv * 16 + g * 4 + rr;
        if (node < n) { s_src[node] = ss[rr]; s_dst[node] = sd[rr]; }
      }
    }
  }
}

// per-block bucket histogram (bucket = dst >> BKSH), LDS atomics only
__global__ __launch_bounds__(256) void k_hist(
    const int* __restrict__ dsts, int* __restrict__ cnt, int e, int nbk, int nblk)
{
  __shared__ int hist[2048];
  const int t = threadIdx.x, b = blockIdx.x;
  for (int k = t; k < nbk; k += 256) hist[k] = 0;
  __syncthreads();
  const int i0 = b * EPB;
  const int iend = min(i0 + EPB, e);
  for (int i = i0 + t; i < iend; i += 256)
    atomicAdd(&hist[dsts[i] >> BKSH], 1);
  __syncthreads();
  for (int k = t; k < nbk; k += 256) cnt[k * nblk + b] = hist[k];
}

// ---- exclusive scan (in-place capable) ----
__global__ __launch_bounds__(256) void k_scan1(
    const int* __restrict__ deg, int* __restrict__ base, int* __restrict__ bsum, int n)
{
  __shared__ int ws[4];
  int t = threadIdx.x;
  int g0 = blockIdx.x * 1024 + t * 4;
  int4 v = make_int4(0, 0, 0, 0);
  if (g0 + 3 < n) v = *(const int4*)(deg + g0);
  else {
    if (g0     < n) v.x = deg[g0];
    if (g0 + 1 < n) v.y = deg[g0 + 1];
    if (g0 + 2 < n) v.z = deg[g0 + 2];
    if (g0 + 3 < n) v.w = deg[g0 + 3];
  }
  int s = v.x + v.y + v.z + v.w;
  int inc = s;
  #pragma unroll
  for (int d = 1; d < 64; d <<= 1) {
    int o = __shfl_up(inc, d);
    if ((t & 63) >= d) inc += o;
  }
  int wid = t >> 6;
  if ((t & 63) == 63) ws[wid] = inc;
  __syncthreads();
  int woff = 0;
  for (int w = 0; w < wid; ++w) woff += ws[w];
  int exc = woff + inc - s;
  if (g0 + 3 < n) {
    *(int4*)(base + g0) = make_int4(exc, exc + v.x, exc + v.x + v.y, exc + v.x + v.y + v.z);
  } else {
    if (g0     < n) base[g0]     = exc;
    if (g0 + 1 < n) base[g0 + 1] = exc + v.x;
    if (g0 + 2 < n) base[g0 + 2] = exc + v.x + v.y;
  }
  if (t == 255) bsum[blockIdx.x] = woff + inc;
}

__global__ __launch_bounds__(256) void k_scan2(
    const int* __restrict__ bsum, int* __restrict__ boff, int nb)
{
  __shared__ int ws[4];
  int t = threadIdx.x;
  int x = t < nb ? bsum[t] : 0;
  int inc = x;
  #pragma unroll
  for (int d = 1; d < 64; d <<= 1) {
    int o = __shfl_up(inc, d);
    if ((t & 63) >= d) inc += o;
  }
  int wid = t >> 6;
  if ((t & 63) == 63) ws[wid] = inc;
  __syncthreads();
  int woff = 0;
  for (int w = 0; w < wid; ++w) woff += ws[w];
  if (t < nb) boff[t] = woff + inc - x;
}

__global__ __launch_bounds__(256) void k_scan3(
    int* __restrict__ base, const int* __restrict__ boff, int n)
{
  int i = blockIdx.x * 256 + threadIdx.x;
  if (i < n) base[i] += boff[i >> 10];
}

// bucket-grouped scatter: payload = src | ty<<17 | (d&63)<<20, LDS cursors
__global__ __launch_bounds__(256) void k_scatter2(
    const int* __restrict__ ei, const int* __restrict__ ey,
    const int* __restrict__ cnt_s, unsigned* __restrict__ rec,
    int e, int nbk, int nblk)
{
  __shared__ int cur[2048];
  const int t = threadIdx.x, b = blockIdx.x;
  for (int k = t; k < nbk; k += 256) cur[k] = cnt_s[k * nblk + b];
  __syncthreads();
  const int i0 = b * EPB;
  const int iend = min(i0 + EPB, e);
  for (int i = i0 + t; i < iend; i += 256) {
    int s = ei[i], d = ei[e + i], ty = ey[i];
    int pos = atomicAdd(&cur[d >> BKSH], 1);
    rec[pos] = (unsigned)s | ((unsigned)ty << 17) | ((unsigned)(d & (BKDST - 1)) << 20);
  }
}

// one block per 64-dst bucket: LDS CSR build + per-dst softmax + gather aggregate
__global__ __launch_bounds__(256) void k_agg2(
    const unsigned* __restrict__ rec, const int* __restrict__ cnt_s,
    const float* __restrict__ s_src, const float* __restrict__ s_dst,
    const _Float16* __restrict__ nfl, _Float16* __restrict__ h,
    int n, int e, int nbk, int nblk)
{
  __shared__ unsigned ord[CAP];
  __shared__ float efl[CAP];
  __shared__ int dcnt[BKDST];
  __shared__ int dbase[BKDST + 1];
  __shared__ float sdl[BKDST];
  const int t = threadIdx.x;
  const int k = blockIdx.x;
  const int d0 = k << BKSH;
  const int ndst = min(BKDST, n - d0);
  const int bs = cnt_s[k * nblk];
  const int be = (k + 1 < nbk) ? cnt_s[(k + 1) * nblk] : e;
  const int cnt = be - bs;
  if (t < BKDST) {
    dcnt[t] = 0;
    if (t < ndst) sdl[t] = s_dst[d0 + t];
  }
  __syncthreads();
  const int g = t >> 4, l = t & 15;

  if (cnt <= CAP) {
    for (int i = t; i < cnt; i += 256)
      atomicAdd(&dcnt[(rec[bs + i] >> 20) & (BKDST - 1)], 1);
    __syncthreads();
    if (t < BKDST) {  // single-wave exclusive scan dcnt -> dbase (+cursor seed)
      int v = dcnt[t];
      int inc = v;
      #pragma unroll
      for (int dd = 1; dd < 64; dd <<= 1) {
        int o = __shfl_up(inc, dd);
        if (t >= dd) inc += o;
      }
      dbase[t] = inc - v;
      dcnt[t]  = inc - v;
      if (t == BKDST - 1) dbase[BKDST] = inc;
    }
    __syncthreads();
    for (int i = t; i < cnt; i += 256) {
      unsigned p = rec[bs + i];
      int pos = atomicAdd(&dcnt[(p >> 20) & (BKDST - 1)], 1);
      ord[pos] = p;
    }
    __syncthreads();
    for (int i = t; i < cnt; i += 256) {
      unsigned p = ord[i];
      float ef = s_src[p & 0x1FFFF] + sdl[(p >> 20) & (BKDST - 1)];
      efl[i] = ef >= 0.f ? ef : 0.2f * ef;
    }
    __syncthreads();
    for (int di = g; di < ndst; di += 16) {
      int s0 = dbase[di], deg = dbase[di + 1] - s0;
      float acc[8] = {0.f, 0.f, 0.f, 0.f, 0.f, 0.f, 0.f, 0.f};
      if (deg > 0) {
        float mx[NTYPES];
        #pragma unroll
        for (int tt = 0; tt < NTYPES; ++tt) mx[tt] = -1e30f;
        for (int j0 = 0; j0 < deg; j0 += 16) {
          int jj = j0 + l;
          bool ok = jj < deg;
          float ef = ok ? efl[s0 + jj] : -1e30f;
          int ty = ok ? (int)((ord[s0 + jj] >> 17) & 7) : 7;
          #pragma unroll
          for (int tt = 0; tt < NTYPES; ++tt) {
            float v = (ty == tt) ? ef : -1e30f;
            v = fmaxf(v, __shfl_xor(v, 1)); v = fmaxf(v, __shfl_xor(v, 2));
            v = fmaxf(v, __shfl_xor(v, 4)); v = fmaxf(v, __shfl_xor(v, 8));
            mx[tt] = fmaxf(mx[tt], v);
          }
        }
        float sm[NTYPES];
        #pragma unroll
        for (int tt = 0; tt < NTYPES; ++tt) sm[tt] = 0.f;
        for (int j0 = 0; j0 < deg; j0 += 16) {
          int jj = j0 + l;
          bool ok = jj < deg;
          int ty = ok ? (int)((ord[s0 + jj] >> 17) & 7) : 7;
          float ex = ok ? __expf(efl[s0 + jj] - mx[ty]) : 0.f;
          if (ok) efl[s0 + jj] = ex;
          #pragma unroll
          for (int tt = 0; tt < NTYPES; ++tt) {
            float v = (ty == tt) ? ex : 0.f;
            v += __shfl_xor(v, 1); v += __shfl_xor(v, 2);
            v += __shfl_xor(v, 4); v += __shfl_xor(v, 8);
            sm[tt] += v;
          }
        }
        float rsm[NTYPES];
        #pragma unroll
        for (int tt = 0; tt < NTYPES; ++tt) rsm[tt] = sm[tt] > 0.f ? 1.f / sm[tt] : 0.f;
        int j = 0;
        for (; j + 2 <= deg; j += 2) {
          unsigned p0 = ord[s0 + j], p1 = ord[s0 + j + 1];
          float a0 = efl[s0 + j] * rsm[(p0 >> 17) & 7];
          float a1 = efl[s0 + j + 1] * rsm[(p1 >> 17) & 7];
          half8 x0 = *(const half8*)(nfl + (size_t)(p0 & 0x1FFFF) * 128 + l * 8);
          half8 x1 = *(const half8*)(nfl + (size_t)(p1 & 0x1FFFF) * 128 + l * 8);
          #pragma unroll
          for (int kk = 0; kk < 8; ++kk) acc[kk] = fmaf(a0, (float)x0[kk], acc[kk]);
          #pragma unroll
          for (int kk = 0; kk < 8; ++kk) acc[kk] = fmaf(a1, (float)x1[kk], acc[kk]);
        }
        if (j < deg) {
          unsigned p0 = ord[s0 + j];
          float a0 = efl[s0 + j] * rsm[(p0 >> 17) & 7];
          half8 x0 = *(const half8*)(nfl + (size_t)(p0 & 0x1FFFF) * 128 + l * 8);
          #pragma unroll
          for (int kk = 0; kk < 8; ++kk) acc[kk] = fmaf(a0, (float)x0[kk], acc[kk]);
        }
      }
      half8 hv;
      #pragma unroll
      for (int kk = 0; kk < 8; ++kk) hv[kk] = (_Float16)acc[kk];
      *(half8*)(h + (size_t)(d0 + di) * 128 + l * 8) = hv;
    }
  } else {
    // fallback (bucket overflow — not expected): stream global rec per dst
    const int gb = (t & 63) & 48;
    for (int di = g; di < ndst; di += 16) {
      float mx[NTYPES], sm[NTYPES];
      #pragma unroll
      for (int tt = 0; tt < NTYPES; ++tt) { mx[tt] = -1e30f; sm[tt] = 0.f; }
      for (int j0 = 0; j0 < cnt; j0 += 16) {
        int jj = j0 + l;
        unsigned p = (jj < cnt) ? rec[bs + jj] : 0xFFFFFFFFu;
        bool mine = (p != 0xFFFFFFFFu) && (int)((p >> 20) & (BKDST - 1)) == di;
        float ef = -1e30f; int ty = 7;
        if (mine) {
          ef = s_src[p & 0x1FFFF] + sdl[di];
          ef = ef >= 0.f ? ef : 0.2f * ef;
          ty = (p >> 17) & 7;
        }
        #pragma unroll
        for (int tt = 0; tt < NTYPES; ++tt) {
          float v = (mine && ty == tt) ? ef : -1e30f;
          v = fmaxf(v, __shfl_xor(v, 1)); v = fmaxf(v, __shfl_xor(v, 2));
          v = fmaxf(v, __shfl_xor(v, 4)); v = fmaxf(v, __shfl_xor(v, 8));
          mx[tt] = fmaxf(mx[tt], v);
        }
      }
      for (int j0 = 0; j0 < cnt; j0 += 16) {
        int jj = j0 + l;
        unsigned p = (jj < cnt) ? rec[bs + jj] : 0xFFFFFFFFu;
        bool mine = (p != 0xFFFFFFFFu) && (int)((p >> 20) & (BKDST - 1)) == di;
        float ex = 0.f; int ty = 7;
        if (mine) {
          float ef = s_src[p & 0x1FFFF] + sdl[di];
          ef = ef >= 0.f ? ef : 0.2f * ef;
          ty = (p >> 17) & 7;
          ex = __expf(ef - mx[ty]);
        }
        #pragma unroll
        for (int tt = 0; tt < NTYPES; ++tt) {
          float v = (ty == tt) ? ex : 0.f;
          v += __shfl_xor(v, 1); v += __shfl_xor(v, 2);
          v += __shfl_xor(v, 4); v += __shfl_xor(v, 8);
          sm[tt] += v;
        }
      }
      float rsm[NTYPES];
      #pragma unroll
      for (int tt = 0; tt < NTYPES; ++tt) rsm[tt] = sm[tt] > 0.f ? 1.f / sm[tt] : 0.f;
      float acc[8] = {0.f, 0.f, 0.f, 0.f, 0.f, 0.f, 0.f, 0.f};
      for (int j0 = 0; j0 < cnt; j0 += 16) {
        int jj = j0 + l;
        unsigned p = (jj < cnt) ? rec[bs + jj] : 0xFFFFFFFFu;
        bool mine = (p != 0xFFFFFFFFu) && (int)((p >> 20) & (BKDST - 1)) == di;
        float al = 0.f;
        if (mine) {
          float ef = s_src[p & 0x1FFFF] + sdl[di];
          ef = ef >= 0.f ? ef : 0.2f * ef;
          int ty = (p >> 17) & 7;
          al = __expf(ef - mx[ty]) * rsm[ty];
        }
        unsigned pv = mine ? p : 0xFFFFFFFFu;
        for (int jj2 = 0; jj2 < 16; ++jj2) {
          unsigned pp = __shfl(pv, gb + jj2);
          float aa = __shfl(al, gb + jj2);
          if (pp != 0xFFFFFFFFu) {
            half8 x = *(const half8*)(nfl + (size_t)(pp & 0x1FFFF) * 128 + l * 8);
            #pragma unroll
            for (int kk = 0; kk < 8; ++kk) acc[kk] = fmaf(aa, (float)x[kk], acc[kk]);
          }
        }
      }
      half8 hv;
      #pragma unroll
      for (int kk = 0; kk < 8; ++kk) hv[kk] = (_Float16)acc[kk];
      *(half8*)(h + (size_t)(d0 + di) * 128 + l * 8) = hv;
    }
  }
}

// out = relu(b + nh @ Wo1^T + h @ Wo2^T), jhalf = blockIdx&1 owns 64 cols
__global__ __launch_bounds__(256) void k_gemmO(
    const float* __restrict__ nh, const _Float16* __restrict__ hbuf,
    const float* __restrict__ Wout, const float* __restrict__ bias,
    float* __restrict__ out, int n)
{
  __shared__ _Float16 w1[64 * 128], w2[64 * 128];
  __shared__ _Float16 x1[64 * 128], x2[64 * 128];
  const int t = threadIdx.x, lane = t & 63, wv = t >> 6;
  const int r16 = lane & 15, g = lane >> 4;
  const int jhalf = blockIdx.x & 1;
  stage_f32(w1, Wout, 64, 64, 0,  jhalf * 64, 1 << 30, t);
  stage_f32(w2, Wout, 64, 64, 32, jhalf * 64, 1 << 30, t);
  float bv[4];
  #pragma unroll
  for (int nf = 0; nf < 4; ++nf) bv[nf] = bias[jhalf * 64 + nf * 16 + r16];
  const int nchunk = (n + 63) >> 6;
  for (int c = blockIdx.x >> 1; c < nchunk; c += gridDim.x >> 1) {
    const int base = c << 6;
    __syncthreads();
    stage_f32(x1, nh, 64, 32, 0, base, n, t);
    stage_h(x2, hbuf, 64, base, n, t);
    __syncthreads();
    float4v acc[4];
    #pragma unroll
    for (int nf = 0; nf < 4; ++nf) acc[nf] = (float4v){0.f, 0.f, 0.f, 0.f};
    #pragma unroll
    for (int s = 0; s < 4; ++s) {
      half8 a1 = frag_ld(x1, wv * 16 + r16, s * 32 + g * 8);
      half8 a2 = frag_ld(x2, wv * 16 + r16, s * 32 + g * 8);
      #pragma unroll
      for (int nf = 0; nf < 4; ++nf) {
        acc[nf] = __builtin_amdgcn_mfma_f32_16x16x32_f16(a1, frag_ld(w1, nf * 16 + r16, s * 32 + g * 8), acc[nf], 0, 0, 0);
        acc[nf] = __builtin_amdgcn_mfma_f32_16x16x32_f16(a2, frag_ld(w2, nf * 16 + r16, s * 32 + g * 8), acc[nf], 0, 0, 0);
      }
    }
    #pragma unroll
    for (int rr = 0; rr < 4; ++rr) {
      int node = base + wv * 16 + g * 4 + rr;
      if (node >= n) continue;
      #pragma unroll
      for (int nf = 0; nf < 4; ++nf)
        out[(size_t)node * 128 + jhalf * 64 + nf * 16 + r16] = fmaxf(acc[nf][rr] + bv[nf], 0.f);
    }
  }
}

extern "C" void kernel_launch(void* const* d_in, const int* in_sizes, int n_in,
                              void* d_out, int out_size, void* d_ws, size_t ws_size,
                              hipStream_t stream) {
  const float* nh     = (const float*)d_in[0];
  const int*   edge_y = (const int*)d_in[1];
  const int*   ei     = (const int*)d_in[2];
  const float* W_nf   = (const float*)d_in[3];
  const float* W_attn = (const float*)d_in[4];
  const float* W_out  = (const float*)d_in[5];
  const float* b_out  = (const float*)d_in[6];
  float* out = (float*)d_out;
  const int n = in_sizes[0] / 128;
  const int e = in_sizes[1];
  const int nbk  = (n + BKDST - 1) >> BKSH;  // buckets of 64 dsts
  const int nblk = (e + EPB - 1) / EPB;      // hist/scatter blocks
  const int ncnt = nbk * nblk;
  const int nb2  = (ncnt + 1023) / 1024;

  // workspace layout
  _Float16* nfl_h = (_Float16*)d_ws;                   // n*128 f16
  _Float16* h_h   = nfl_h + (size_t)n * 128;           // n*128 f16
  float* s_src = (float*)(h_h + (size_t)n * 128);      // n
  float* s_dst = s_src + n;                            // n
  int*   cnt   = (int*)(s_dst + n);                    // nbk*nblk
  int*   bsum  = cnt + ncnt;                           // 256
  int*   boff  = bsum + 256;                           // 256
  unsigned* rec = (unsigned*)(boff + 256);             // e

  // 1) nfl(f16) = nh @ W_nf^T ; s_src/s_dst
  k_gemm0<<<768, 256, 0, stream>>>(nh, W_nf, W_attn, s_src, s_dst, nfl_h, n);
  // 2) bucket histogram + scan (in-place)
  k_hist<<<nblk, 256, 0, stream>>>(ei + e, cnt, e, nbk, nblk);
  k_scan1<<<nb2, 256, 0, stream>>>(cnt, cnt, bsum, ncnt);
  k_scan2<<<1, 256, 0, stream>>>(bsum, boff, nb2);
  k_scan3<<<(ncnt + 255) / 256, 256, 0, stream>>>(cnt, boff, ncnt);
  // 3) bucket-grouped scatter (4B payload, contiguous segments)
  k_scatter2<<<nblk, 256, 0, stream>>>(ei, edge_y, cnt, rec, e, nbk, nblk);
  // 4) per-bucket LDS CSR + softmax + aggregate -> h (f16)
  k_agg2<<<nbk, 256, 0, stream>>>(rec, cnt, s_src, s_dst, nfl_h, h_h, n, e, nbk, nblk);
  // 5) out = relu(b + nh@Wo1^T + h@Wo2^T)
  k_gemmO<<<1024, 256, 0, stream>>>(nh, h_h, W_out, b_out, out, n);
}